// Round 8
// baseline (257.402 us; speedup 1.0000x reference)
//
#include <hip/hip_runtime.h>
#include <hip/hip_bf16.h>

#define DIM   1024
#define NHEAD 16
#define HDIM  64
#define BATCH 4
#define SEQ   1024
#define MTOT  (BATCH*SEQ)   // 4096
#define DFF   (4*DIM)       // 4096
#define LDQ   3072          // fused QKV row stride

typedef _Float16 f16x8 __attribute__((ext_vector_type(8)));
typedef _Float16 f16x4 __attribute__((ext_vector_type(4)));
typedef float    f32x4 __attribute__((ext_vector_type(4)));

// gelu(x) = 0.5x(1+tanh(z)) == x * sigmoid(2z), z = c(x + 0.044715 x^3).
__device__ __forceinline__ float geluf(float x) {
    float z2 = 1.5957691216057308f * (x + 0.044715f * x * x * x);  // 2*c*(...)
    return x * __builtin_amdgcn_rcpf(1.0f + __expf(-z2));
}

// Swizzled LDS byte offset for tiles with 64-f16 (128 B) rows, 8 slots of 16 B.
__device__ __forceinline__ int swz_off(int row, int slot) {
    return row * 128 + ((slot ^ (row & 7)) << 4);
}
__device__ __forceinline__ f16x8 ldsfrag(const _Float16* s, int row, int slot) {
    return *(const f16x8*)((const char*)s + swz_off(row, slot));
}

// Async global->LDS staging: linear LDS dest (wave-uniform base + lane*16),
// inverse-swizzled GLOBAL source so stored layout == swizzled layout (m173).
template <int NCHUNK>
__device__ __forceinline__ void stage_async(const _Float16* __restrict__ g, int ld,
                                            _Float16* s, int w, int lane) {
    int r_in = lane >> 3;               // 0..7 row within chunk
    int sslot = lane & 7;               // stored 16B slot
    int lslot = sslot ^ r_in;           // logical slot (row&7 == r_in)
#pragma unroll
    for (int q = 0; q < NCHUNK; ++q) {
        int chunk = w * NCHUNK + q;
        int row = chunk * 8 + r_in;
        const _Float16* gp = g + (size_t)row * ld + lslot * 8;
        _Float16* sp = s + chunk * 512;  // wave-uniform
        __builtin_amdgcn_global_load_lds(
            (const __attribute__((address_space(1))) void*)gp,
            (__attribute__((address_space(3))) void*)sp, 16, 0, 0);
    }
}

// ---------------- transpose + fp32->f16 convert:  src[K][N] -> dst[N][K] ----
__global__ __launch_bounds__(256) void k_tcvt(const float* __restrict__ src,
                                              _Float16* __restrict__ dst,
                                              int K, int N) {
    __shared__ float tile[32][33];
    int n0 = blockIdx.x * 32, k0 = blockIdx.y * 32;
    int tx = threadIdx.x, ty = threadIdx.y;
#pragma unroll
    for (int i = 0; i < 32; i += 8)
        tile[ty + i][tx] = src[(size_t)(k0 + ty + i) * N + (n0 + tx)];
    __syncthreads();
#pragma unroll
    for (int i = 0; i < 32; i += 8)
        dst[(size_t)(n0 + ty + i) * K + (k0 + tx)] = (_Float16)tile[tx][ty + i];
}

// three 1024x1024 transposes in one launch (z picks the source)
__global__ __launch_bounds__(256) void k_tcvt3(const float* __restrict__ s0,
                                               const float* __restrict__ s1,
                                               const float* __restrict__ s2,
                                               _Float16* __restrict__ dst) {
    __shared__ float tile[32][33];
    const float* src = blockIdx.z == 0 ? s0 : (blockIdx.z == 1 ? s1 : s2);
    _Float16* d = dst + (size_t)blockIdx.z * (1024 * 1024);
    int n0 = blockIdx.x * 32, k0 = blockIdx.y * 32;
    int tx = threadIdx.x, ty = threadIdx.y;
#pragma unroll
    for (int i = 0; i < 32; i += 8)
        tile[ty + i][tx] = src[(size_t)(k0 + ty + i) * 1024 + (n0 + tx)];
    __syncthreads();
#pragma unroll
    for (int i = 0; i < 32; i += 8)
        d[(size_t)(n0 + ty + i) * 1024 + (k0 + tx)] = (_Float16)tile[tx][ty + i];
}

// ---------------- LayerNorm (fp32 in -> f16 out), one block per row ---------
__global__ __launch_bounds__(256) void k_ln(const float* __restrict__ x,
                                            const float* __restrict__ sc,
                                            const float* __restrict__ sh,
                                            _Float16* __restrict__ out) {
    int row = blockIdx.x;
    int t = threadIdx.x;
    float4 v = ((const float4*)(x + (size_t)row * DIM))[t];
    float sum = v.x + v.y + v.z + v.w;
    float sq  = v.x * v.x + v.y * v.y + v.z * v.z + v.w * v.w;
#pragma unroll
    for (int m = 1; m < 64; m <<= 1) {
        sum += __shfl_xor(sum, m);
        sq  += __shfl_xor(sq, m);
    }
    __shared__ float rs[4], rq[4];
    int w = t >> 6;
    if ((t & 63) == 0) { rs[w] = sum; rq[w] = sq; }
    __syncthreads();
    sum = rs[0] + rs[1] + rs[2] + rs[3];
    sq  = rq[0] + rq[1] + rq[2] + rq[3];
    float mean = sum * (1.0f / DIM);
    float var  = sq * (1.0f / DIM) - mean * mean;
    float rstd = rsqrtf(var + 1e-5f);
    float4 s4 = ((const float4*)sc)[t];
    float4 b4 = ((const float4*)sh)[t];
    f16x4 o;
    o[0] = (_Float16)(s4.x * ((v.x - mean) * rstd) + b4.x);
    o[1] = (_Float16)(s4.y * ((v.y - mean) * rstd) + b4.y);
    o[2] = (_Float16)(s4.z * ((v.z - mean) * rstd) + b4.z);
    o[3] = (_Float16)(s4.w * ((v.w - mean) * rstd) + b4.w);
    ((f16x4*)(out + (size_t)row * DIM))[t] = o;
}

// ---------------- GEMM 128x128, BK=64, 2-phase pipelined, XCD-chunked -------
// 1D grid; bijective XCD swizzle: lin = (bid&7)*(nwg/8) + bid>>3 gives each
// XCD a contiguous chunk of n-fastest tile ids -> A-panels L2-resident per
// XCD, B streamed in lockstep K-slices (T1; nwg%8==0 for all launches).
// EPI: 0 = plain f16; 1 = +bias,gelu f16; 2 = +bias,+resid -> f32
template <int EPI>
__global__ __launch_bounds__(256) void k_gemm(const _Float16* __restrict__ A,
                                              const _Float16* __restrict__ BT,
                                              int N, int K, int gx,
                                              _Float16* __restrict__ Ch,
                                              float* __restrict__ Cf,
                                              const float* __restrict__ bias,
                                              const float* __restrict__ resid) {
    __shared__ _Float16 As[2][128 * 64];
    __shared__ _Float16 Bs[2][128 * 64];
    int t = threadIdx.x;
    int bid = blockIdx.x;
    int lin = (bid & 7) * ((int)gridDim.x >> 3) + (bid >> 3);
    int m0 = (lin / gx) * 128, n0 = (lin % gx) * 128;
    int lane = t & 63, w = t >> 6;
    int wm = (w >> 1) * 64, wn = (w & 1) * 64;
    int lr = lane & 15, lg = lane >> 4;
    f32x4 acc[4][4];
#pragma unroll
    for (int i = 0; i < 4; ++i)
#pragma unroll
        for (int j = 0; j < 4; ++j) acc[i][j] = (f32x4){0.f, 0.f, 0.f, 0.f};

    const _Float16* Ag = A  + (size_t)m0 * K;
    const _Float16* Bg = BT + (size_t)n0 * K;
    int nt = K / 64;
    stage_async<4>(Ag, K, As[0], w, lane);
    stage_async<4>(Bg, K, Bs[0], w, lane);
    __syncthreads();
    for (int tt = 0; tt < nt; ++tt) {
        int cur = tt & 1, nxt = cur ^ 1;
        if (tt + 1 < nt) {
            stage_async<4>(Ag + (tt + 1) * 64, K, As[nxt], w, lane);
            stage_async<4>(Bg + (tt + 1) * 64, K, Bs[nxt], w, lane);
        }
#pragma unroll
        for (int kk = 0; kk < 2; ++kk) {
            f16x8 a[4], b[4];
#pragma unroll
            for (int i = 0; i < 4; ++i) a[i] = ldsfrag(As[cur], wm + i * 16 + lr, kk * 4 + lg);
#pragma unroll
            for (int j = 0; j < 4; ++j) b[j] = ldsfrag(Bs[cur], wn + j * 16 + lr, kk * 4 + lg);
            __builtin_amdgcn_s_setprio(1);
#pragma unroll
            for (int i = 0; i < 4; ++i)
#pragma unroll
                for (int j = 0; j < 4; ++j)
                    acc[i][j] = __builtin_amdgcn_mfma_f32_16x16x32_f16(a[i], b[j], acc[i][j], 0, 0, 0);
            __builtin_amdgcn_s_setprio(0);
        }
        __syncthreads();   // drains next-tile loads; guards buffer reuse
    }
#pragma unroll
    for (int i = 0; i < 4; ++i) {
#pragma unroll
        for (int j = 0; j < 4; ++j) {
            int row = m0 + wm + i * 16 + lg * 4;
            int col = n0 + wn + j * 16 + lr;
#pragma unroll
            for (int r = 0; r < 4; ++r) {
                float v = acc[i][j][r];
                size_t idx = (size_t)(row + r) * N + col;
                if constexpr (EPI == 0)      Ch[idx] = (_Float16)v;
                else if constexpr (EPI == 1) Ch[idx] = (_Float16)geluf(v + bias[col]);
                else                         Cf[idx] = v + bias[col] + resid[idx];
            }
        }
    }
}

// ---------------- Flash attention: 1 wave per (b, h, 32-row q-tile) ---------
// Barrier-free per-wave structure + LPT heavy-first 1D grid.
__global__ __launch_bounds__(64) void k_attn(const _Float16* __restrict__ QKV,
                                             _Float16* __restrict__ Og) {
    __shared__ _Float16 Vt[64 * 64];  // V^T [d][k], swizzled (8 KB)
    __shared__ _Float16 Ps[32 * 64];  // P[q][k], swizzled (4 KB)
    int lane = threadIdx.x;
    int id = blockIdx.x;
    int bh = id & 63;
    int qt = (SEQ / 32 - 1) - (id >> 6);  // heavy blocks dispatch first
    int h = bh & 15, b = bh >> 4;
    int q0 = qt * 32;
    int lr = lane & 15, lg = lane >> 4;
    size_t base = (size_t)b * SEQ;
    int cq = h * HDIM, ck = 1024 + h * HDIM, cv = 2048 + h * HDIM;

    // Q fragments in registers, pre-scaled by 1/sqrt(HD)
    f16x8 aq[2][2];
#pragma unroll
    for (int i = 0; i < 2; ++i)
#pragma unroll
        for (int kk = 0; kk < 2; ++kk) {
            f16x8 v = *(const f16x8*)(QKV + (base + q0 + i * 16 + lr) * LDQ + cq + kk * 32 + lg * 8);
#pragma unroll
            for (int e = 0; e < 8; ++e) v[e] = v[e] * (_Float16)0.125f;
            aq[i][kk] = v;
        }

    f32x4 cacc[2][4];
#pragma unroll
    for (int i = 0; i < 2; ++i)
#pragma unroll
        for (int j = 0; j < 4; ++j) cacc[i][j] = (f32x4){0.f, 0.f, 0.f, 0.f};
    float mrun[2][4], lrun[2][4];
#pragma unroll
    for (int i = 0; i < 2; ++i)
#pragma unroll
        for (int r = 0; r < 4; ++r) { mrun[i][r] = -1e30f; lrun[i][r] = 0.f; }

    int ntiles = q0 / 64 + 1;   // 64-wide K/V tiles needed for causal rows
    for (int kt = 0; kt < ntiles; ++kt) {
        int k0 = kt * 64;
        // stage V^T into LDS (scalar transposed writes, swizzled; 2-way = free)
        {
            const _Float16* vr = QKV + (base + k0 + lane) * LDQ + cv;
            int kslot = lane >> 3;
            int kb2 = (lane & 7) * 2;
#pragma unroll
            for (int part = 0; part < 8; ++part) {
                f16x8 v8 = *(const f16x8*)(vr + part * 8);
#pragma unroll
                for (int e = 0; e < 8; ++e) {
                    int d = part * 8 + e;
                    *(_Float16*)((char*)Vt + d * 128 + ((kslot ^ (d & 7)) << 4) + kb2) = v8[e];
                }
            }
        }
        // scores = Q K^T (K fragments straight from global, L2-hot)
        f32x4 sacc[2][4];
#pragma unroll
        for (int i = 0; i < 2; ++i)
#pragma unroll
            for (int j = 0; j < 4; ++j) sacc[i][j] = (f32x4){0.f, 0.f, 0.f, 0.f};
#pragma unroll
        for (int kk = 0; kk < 2; ++kk) {
            f16x8 bk[4];
#pragma unroll
            for (int j = 0; j < 4; ++j)
                bk[j] = *(const f16x8*)(QKV + (base + k0 + j * 16 + lr) * LDQ + ck + kk * 32 + lg * 8);
            __builtin_amdgcn_s_setprio(1);
#pragma unroll
            for (int i = 0; i < 2; ++i)
#pragma unroll
                for (int j = 0; j < 4; ++j)
                    sacc[i][j] = __builtin_amdgcn_mfma_f32_16x16x32_f16(aq[i][kk], bk[j], sacc[i][j], 0, 0, 0);
            __builtin_amdgcn_s_setprio(0);
        }
        // causal mask (last tile only; global coords)
        if (kt == ntiles - 1) {
#pragma unroll
            for (int i = 0; i < 2; ++i)
#pragma unroll
                for (int j = 0; j < 4; ++j)
#pragma unroll
                    for (int r = 0; r < 4; ++r) {
                        int qq = q0 + i * 16 + lg * 4 + r;
                        int kc = k0 + j * 16 + lr;
                        if (kc > qq) sacc[i][j][r] = -1e30f;
                    }
        }
        // online softmax (rows spread over 16 lanes)
#pragma unroll
        for (int i = 0; i < 2; ++i) {
            float mn[4], al[4];
#pragma unroll
            for (int r = 0; r < 4; ++r) {
                float tm = fmaxf(fmaxf(sacc[i][0][r], sacc[i][1][r]),
                                 fmaxf(sacc[i][2][r], sacc[i][3][r]));
#pragma unroll
                for (int msk = 1; msk < 16; msk <<= 1) tm = fmaxf(tm, __shfl_xor(tm, msk));
                float m2 = fmaxf(mrun[i][r], tm);
                al[r] = __expf(mrun[i][r] - m2);
                mrun[i][r] = m2;
                mn[r] = m2;
            }
#pragma unroll
            for (int jd = 0; jd < 4; ++jd)
#pragma unroll
                for (int r = 0; r < 4; ++r) cacc[i][jd][r] *= al[r];
#pragma unroll
            for (int r = 0; r < 4; ++r) {
                float ps = 0.f;
#pragma unroll
                for (int j = 0; j < 4; ++j) {
                    float p = __expf(sacc[i][j][r] - mn[r]);
                    sacc[i][j][r] = p;
                    ps += p;
                }
#pragma unroll
                for (int msk = 1; msk < 16; msk <<= 1) ps += __shfl_xor(ps, msk);
                lrun[i][r] = lrun[i][r] * al[r] + ps;
            }
        }
        // P -> LDS (f16, swizzled A-operand layout)
#pragma unroll
        for (int i = 0; i < 2; ++i)
#pragma unroll
            for (int j = 0; j < 4; ++j) {
                int kc = j * 16 + lr;
                int ks = kc >> 3;
                int kb = (kc & 7) * 2;
#pragma unroll
                for (int r = 0; r < 4; ++r) {
                    int qq = i * 16 + lg * 4 + r;
                    *(_Float16*)((char*)Ps + qq * 128 + ((ks ^ (qq & 7)) << 4) + kb) =
                        (_Float16)sacc[i][j][r];
                }
            }
        // PV accumulate (same-wave LDS RAW; in-order per-wave DS pipe)
#pragma unroll
        for (int kk = 0; kk < 2; ++kk) {
            f16x8 pa[2], bv[4];
#pragma unroll
            for (int i = 0; i < 2; ++i)   pa[i]  = ldsfrag(Ps, i * 16 + lr,  kk * 4 + lg);
#pragma unroll
            for (int jd = 0; jd < 4; ++jd) bv[jd] = ldsfrag(Vt, jd * 16 + lr, kk * 4 + lg);
            __builtin_amdgcn_s_setprio(1);
#pragma unroll
            for (int i = 0; i < 2; ++i)
#pragma unroll
                for (int jd = 0; jd < 4; ++jd)
                    cacc[i][jd] = __builtin_amdgcn_mfma_f32_16x16x32_f16(pa[i], bv[jd], cacc[i][jd], 0, 0, 0);
            __builtin_amdgcn_s_setprio(0);
        }
    }
    // normalize + write ctx in [b*S+s][h*64+d] layout
#pragma unroll
    for (int i = 0; i < 2; ++i)
#pragma unroll
        for (int jd = 0; jd < 4; ++jd)
#pragma unroll
            for (int r = 0; r < 4; ++r) {
                int qq = q0 + i * 16 + lg * 4 + r;
                int d = h * HDIM + jd * 16 + lr;
                Og[(base + qq) * DIM + d] = (_Float16)(cacc[i][jd][r] / lrun[i][r]);
            }
}

// ---------------------------------------------------------------------------
extern "C" void kernel_launch(void* const* d_in, const int* in_sizes, int n_in,
                              void* d_out, int out_size, void* d_ws, size_t ws_size,
                              hipStream_t stream) {
    const float* x    = (const float*)d_in[0];
    const float* WQ   = (const float*)d_in[1];
    const float* WK   = (const float*)d_in[2];
    const float* WV   = (const float*)d_in[3];
    const float* Wo   = (const float*)d_in[4];
    const float* bo   = (const float*)d_in[5];
    const float* W1   = (const float*)d_in[6];
    const float* b1   = (const float*)d_in[7];
    const float* W2   = (const float*)d_in[8];
    const float* b2   = (const float*)d_in[9];
    const float* ln1s = (const float*)d_in[10];
    const float* ln1b = (const float*)d_in[11];
    const float* ln2s = (const float*)d_in[12];
    const float* ln2b = (const float*)d_in[13];
    float* out = (float*)d_out;
    char* ws = (char*)d_ws;
    const size_t MB = 1024 * 1024;
    _Float16* WTqkv = (_Float16*)(ws + 0 * MB);   // [3072][1024] = 6MB
    _Float16* WTo   = (_Float16*)(ws + 6 * MB);
    _Float16* WT1   = (_Float16*)(ws + 8 * MB);   // [4096][1024]
    _Float16* WT2   = (_Float16*)(ws + 16 * MB);  // [1024][4096]
    _Float16* h1    = (_Float16*)(ws + 24 * MB);
    _Float16* qkvb  = (_Float16*)(ws + 32 * MB);  // [4096][3072] = 24MB
    _Float16* ctx   = (_Float16*)(ws + 56 * MB);
    _Float16* h2    = (_Float16*)(ws + 64 * MB);
    _Float16* ff1   = (_Float16*)(ws + 72 * MB);  // [4096][4096] = 32MB
    float*    x2    = (float*)   (ws + 104 * MB); // fp32 residual = 16MB

    dim3 tb(32, 8);
    k_tcvt3<<<dim3(32, 32, 3), tb, 0, stream>>>(WQ, WK, WV, WTqkv);
    k_tcvt<<<dim3(32, 32), tb, 0, stream>>>(Wo, WTo, 1024, 1024);
    k_tcvt<<<dim3(128, 32), tb, 0, stream>>>(W1, WT1, 1024, 4096);
    k_tcvt<<<dim3(32, 128), tb, 0, stream>>>(W2, WT2, 4096, 1024);

    k_ln<<<MTOT, 256, 0, stream>>>(x, ln1s, ln1b, h1);

    // fused QKV: [4096,1024] x [1024,3072] -> [4096,3072]  (24x32 tiles)
    k_gemm<0><<<dim3(768), 256, 0, stream>>>(h1, WTqkv, LDQ, DIM, 24, qkvb, nullptr, nullptr, nullptr);

    k_attn<<<dim3(2048), 64, 0, stream>>>(qkvb, ctx);

    // x2 = x + ctx @ Wo + bo   (8x32 tiles)
    k_gemm<2><<<dim3(256), 256, 0, stream>>>(ctx, WTo, DIM, DIM, 8, nullptr, x2, bo, x);

    k_ln<<<MTOT, 256, 0, stream>>>(x2, ln2s, ln2b, h2);

    // ff1 = gelu(h2 @ W1 + b1)  (32x32 tiles)
    k_gemm<1><<<dim3(1024), 256, 0, stream>>>(h2, WT1, DFF, DIM, 32, ff1, nullptr, b1, nullptr);

    // out = x2 + ff1 @ W2 + b2  (8x32 tiles)
    k_gemm<2><<<dim3(256), 256, 0, stream>>>(ff1, WT2, DIM, DFF, 8, nullptr, out, b2, x2);
}

// Round 9
// 243.291 us; speedup vs baseline: 1.0580x; 1.0580x over previous
//
#include <hip/hip_runtime.h>
#include <hip/hip_bf16.h>

#define DIM   1024
#define NHEAD 16
#define HDIM  64
#define BATCH 4
#define SEQ   1024
#define MTOT  (BATCH*SEQ)   // 4096
#define DFF   (4*DIM)       // 4096
#define LDQ   3072          // fused QKV row stride

typedef _Float16 f16x8 __attribute__((ext_vector_type(8)));
typedef _Float16 f16x4 __attribute__((ext_vector_type(4)));
typedef float    f32x4 __attribute__((ext_vector_type(4)));

// gelu(x) = 0.5x(1+tanh(z)) == x * sigmoid(2z), z = c(x + 0.044715 x^3).
__device__ __forceinline__ float geluf(float x) {
    float z2 = 1.5957691216057308f * (x + 0.044715f * x * x * x);  // 2*c*(...)
    return x * __builtin_amdgcn_rcpf(1.0f + __expf(-z2));
}

// Swizzled LDS byte offset for tiles with 64-f16 (128 B) rows, 8 slots of 16 B.
__device__ __forceinline__ int swz_off(int row, int slot) {
    return row * 128 + ((slot ^ (row & 7)) << 4);
}
__device__ __forceinline__ f16x8 ldsfrag(const _Float16* s, int row, int slot) {
    return *(const f16x8*)((const char*)s + swz_off(row, slot));
}

// Async global->LDS staging: linear LDS dest (wave-uniform base + lane*16),
// inverse-swizzled GLOBAL source so stored layout == swizzled layout (m173).
template <int NCHUNK>
__device__ __forceinline__ void stage_async(const _Float16* __restrict__ g, int ld,
                                            _Float16* s, int w, int lane) {
    int r_in = lane >> 3;               // 0..7 row within chunk
    int sslot = lane & 7;               // stored 16B slot
    int lslot = sslot ^ r_in;           // logical slot (row&7 == r_in)
#pragma unroll
    for (int q = 0; q < NCHUNK; ++q) {
        int chunk = w * NCHUNK + q;
        int row = chunk * 8 + r_in;
        const _Float16* gp = g + (size_t)row * ld + lslot * 8;
        _Float16* sp = s + chunk * 512;  // wave-uniform
        __builtin_amdgcn_global_load_lds(
            (const __attribute__((address_space(1))) void*)gp,
            (__attribute__((address_space(3))) void*)sp, 16, 0, 0);
    }
}

// ---------------- transpose + fp32->f16 convert:  src[K][N] -> dst[N][K] ----
__global__ __launch_bounds__(256) void k_tcvt(const float* __restrict__ src,
                                              _Float16* __restrict__ dst,
                                              int K, int N) {
    __shared__ float tile[32][33];
    int n0 = blockIdx.x * 32, k0 = blockIdx.y * 32;
    int tx = threadIdx.x, ty = threadIdx.y;
#pragma unroll
    for (int i = 0; i < 32; i += 8)
        tile[ty + i][tx] = src[(size_t)(k0 + ty + i) * N + (n0 + tx)];
    __syncthreads();
#pragma unroll
    for (int i = 0; i < 32; i += 8)
        dst[(size_t)(n0 + ty + i) * K + (k0 + tx)] = (_Float16)tile[tx][ty + i];
}

// three 1024x1024 transposes in one launch (z picks the source)
__global__ __launch_bounds__(256) void k_tcvt3(const float* __restrict__ s0,
                                               const float* __restrict__ s1,
                                               const float* __restrict__ s2,
                                               _Float16* __restrict__ dst) {
    __shared__ float tile[32][33];
    const float* src = blockIdx.z == 0 ? s0 : (blockIdx.z == 1 ? s1 : s2);
    _Float16* d = dst + (size_t)blockIdx.z * (1024 * 1024);
    int n0 = blockIdx.x * 32, k0 = blockIdx.y * 32;
    int tx = threadIdx.x, ty = threadIdx.y;
#pragma unroll
    for (int i = 0; i < 32; i += 8)
        tile[ty + i][tx] = src[(size_t)(k0 + ty + i) * 1024 + (n0 + tx)];
    __syncthreads();
#pragma unroll
    for (int i = 0; i < 32; i += 8)
        d[(size_t)(n0 + ty + i) * 1024 + (k0 + tx)] = (_Float16)tile[tx][ty + i];
}

// ---------------- LayerNorm (fp32 in -> f16 out), one block per row ---------
__global__ __launch_bounds__(256) void k_ln(const float* __restrict__ x,
                                            const float* __restrict__ sc,
                                            const float* __restrict__ sh,
                                            _Float16* __restrict__ out) {
    int row = blockIdx.x;
    int t = threadIdx.x;
    float4 v = ((const float4*)(x + (size_t)row * DIM))[t];
    float sum = v.x + v.y + v.z + v.w;
    float sq  = v.x * v.x + v.y * v.y + v.z * v.z + v.w * v.w;
#pragma unroll
    for (int m = 1; m < 64; m <<= 1) {
        sum += __shfl_xor(sum, m);
        sq  += __shfl_xor(sq, m);
    }
    __shared__ float rs[4], rq[4];
    int w = t >> 6;
    if ((t & 63) == 0) { rs[w] = sum; rq[w] = sq; }
    __syncthreads();
    sum = rs[0] + rs[1] + rs[2] + rs[3];
    sq  = rq[0] + rq[1] + rq[2] + rq[3];
    float mean = sum * (1.0f / DIM);
    float var  = sq * (1.0f / DIM) - mean * mean;
    float rstd = rsqrtf(var + 1e-5f);
    float4 s4 = ((const float4*)sc)[t];
    float4 b4 = ((const float4*)sh)[t];
    f16x4 o;
    o[0] = (_Float16)(s4.x * ((v.x - mean) * rstd) + b4.x);
    o[1] = (_Float16)(s4.y * ((v.y - mean) * rstd) + b4.y);
    o[2] = (_Float16)(s4.z * ((v.z - mean) * rstd) + b4.z);
    o[3] = (_Float16)(s4.w * ((v.w - mean) * rstd) + b4.w);
    ((f16x4*)(out + (size_t)row * DIM))[t] = o;
}

// ---------------- GEMM 128x128, BK=64, 2-phase pipelined, XCD-chunked -------
// (for N>=3072 outputs: QKV, FF1 — grids 768/1024 blocks)
// EPI: 0 = plain f16; 1 = +bias,gelu f16
template <int EPI>
__global__ __launch_bounds__(256) void k_gemm(const _Float16* __restrict__ A,
                                              const _Float16* __restrict__ BT,
                                              int N, int K, int gx,
                                              _Float16* __restrict__ Ch,
                                              const float* __restrict__ bias) {
    __shared__ _Float16 As[2][128 * 64];
    __shared__ _Float16 Bs[2][128 * 64];
    int t = threadIdx.x;
    int bid = blockIdx.x;
    int lin = (bid & 7) * ((int)gridDim.x >> 3) + (bid >> 3);
    int m0 = (lin / gx) * 128, n0 = (lin % gx) * 128;
    int lane = t & 63, w = t >> 6;
    int wm = (w >> 1) * 64, wn = (w & 1) * 64;
    int lr = lane & 15, lg = lane >> 4;
    f32x4 acc[4][4];
#pragma unroll
    for (int i = 0; i < 4; ++i)
#pragma unroll
        for (int j = 0; j < 4; ++j) acc[i][j] = (f32x4){0.f, 0.f, 0.f, 0.f};

    const _Float16* Ag = A  + (size_t)m0 * K;
    const _Float16* Bg = BT + (size_t)n0 * K;
    int nt = K / 64;
    stage_async<4>(Ag, K, As[0], w, lane);
    stage_async<4>(Bg, K, Bs[0], w, lane);
    __syncthreads();
    for (int tt = 0; tt < nt; ++tt) {
        int cur = tt & 1, nxt = cur ^ 1;
        if (tt + 1 < nt) {
            stage_async<4>(Ag + (tt + 1) * 64, K, As[nxt], w, lane);
            stage_async<4>(Bg + (tt + 1) * 64, K, Bs[nxt], w, lane);
        }
#pragma unroll
        for (int kk = 0; kk < 2; ++kk) {
            f16x8 a[4], b[4];
#pragma unroll
            for (int i = 0; i < 4; ++i) a[i] = ldsfrag(As[cur], wm + i * 16 + lr, kk * 4 + lg);
#pragma unroll
            for (int j = 0; j < 4; ++j) b[j] = ldsfrag(Bs[cur], wn + j * 16 + lr, kk * 4 + lg);
            __builtin_amdgcn_s_setprio(1);
#pragma unroll
            for (int i = 0; i < 4; ++i)
#pragma unroll
                for (int j = 0; j < 4; ++j)
                    acc[i][j] = __builtin_amdgcn_mfma_f32_16x16x32_f16(a[i], b[j], acc[i][j], 0, 0, 0);
            __builtin_amdgcn_s_setprio(0);
        }
        __syncthreads();   // drains next-tile loads; guards buffer reuse
    }
#pragma unroll
    for (int i = 0; i < 4; ++i) {
#pragma unroll
        for (int j = 0; j < 4; ++j) {
            int row = m0 + wm + i * 16 + lg * 4;
            int col = n0 + wn + j * 16 + lr;
#pragma unroll
            for (int r = 0; r < 4; ++r) {
                float v = acc[i][j][r];
                size_t idx = (size_t)(row + r) * N + col;
                if constexpr (EPI == 0) Ch[idx] = (_Float16)v;
                else                    Ch[idx] = (_Float16)geluf(v + bias[col]);
            }
        }
    }
}

// ---------------- GEMM 128x64 (N=1024 outputs: Wo, FF2), 2-phase + XCD ------
// 512 blocks -> 2 blocks/CU (48KB LDS); XCD chunk: 64 blocks/XCD = 4 m-panels
// x all 16 n-tiles -> A slice <=4MB L2-resident, B once from HBM then L3.
__global__ __launch_bounds__(256) void k_gemm64(const _Float16* __restrict__ A,
                                                const _Float16* __restrict__ BT,
                                                int N, int K,
                                                float* __restrict__ Cf,
                                                const float* __restrict__ bias,
                                                const float* __restrict__ resid) {
    __shared__ _Float16 As[2][128 * 64];
    __shared__ _Float16 Bs[2][64 * 64];
    int t = threadIdx.x;
    int bid = blockIdx.x;
    int lin = (bid & 7) * ((int)gridDim.x >> 3) + (bid >> 3);
    int gx = N / 64;
    int m0 = (lin / gx) * 128, n0 = (lin % gx) * 64;
    int lane = t & 63, w = t >> 6;
    int wm = w * 32;
    int lr = lane & 15, lg = lane >> 4;
    f32x4 acc[2][4];
#pragma unroll
    for (int i = 0; i < 2; ++i)
#pragma unroll
        for (int j = 0; j < 4; ++j) acc[i][j] = (f32x4){0.f, 0.f, 0.f, 0.f};

    const _Float16* Ag = A  + (size_t)m0 * K;
    const _Float16* Bg = BT + (size_t)n0 * K;
    int nt = K / 64;
    stage_async<4>(Ag, K, As[0], w, lane);
    stage_async<2>(Bg, K, Bs[0], w, lane);
    __syncthreads();
    for (int tt = 0; tt < nt; ++tt) {
        int cur = tt & 1, nxt = cur ^ 1;
        if (tt + 1 < nt) {
            stage_async<4>(Ag + (tt + 1) * 64, K, As[nxt], w, lane);
            stage_async<2>(Bg + (tt + 1) * 64, K, Bs[nxt], w, lane);
        }
#pragma unroll
        for (int kk = 0; kk < 2; ++kk) {
            f16x8 a[2], b[4];
#pragma unroll
            for (int i = 0; i < 2; ++i) a[i] = ldsfrag(As[cur], wm + i * 16 + lr, kk * 4 + lg);
#pragma unroll
            for (int j = 0; j < 4; ++j) b[j] = ldsfrag(Bs[cur], j * 16 + lr, kk * 4 + lg);
            __builtin_amdgcn_s_setprio(1);
#pragma unroll
            for (int i = 0; i < 2; ++i)
#pragma unroll
                for (int j = 0; j < 4; ++j)
                    acc[i][j] = __builtin_amdgcn_mfma_f32_16x16x32_f16(a[i], b[j], acc[i][j], 0, 0, 0);
            __builtin_amdgcn_s_setprio(0);
        }
        __syncthreads();
    }
#pragma unroll
    for (int i = 0; i < 2; ++i) {
#pragma unroll
        for (int j = 0; j < 4; ++j) {
            int row = m0 + wm + i * 16 + lg * 4;
            int col = n0 + j * 16 + lr;
#pragma unroll
            for (int r = 0; r < 4; ++r) {
                size_t idx = (size_t)(row + r) * N + col;
                Cf[idx] = acc[i][j][r] + bias[col] + resid[idx];
            }
        }
    }
}

// ---------------- Flash attention: 1 wave per (b, h, 32-row q-tile) ---------
// Barrier-free per-wave structure + LPT heavy-first 1D grid.
__global__ __launch_bounds__(64) void k_attn(const _Float16* __restrict__ QKV,
                                             _Float16* __restrict__ Og) {
    __shared__ _Float16 Vt[64 * 64];  // V^T [d][k], swizzled (8 KB)
    __shared__ _Float16 Ps[32 * 64];  // P[q][k], swizzled (4 KB)
    int lane = threadIdx.x;
    int id = blockIdx.x;
    int bh = id & 63;
    int qt = (SEQ / 32 - 1) - (id >> 6);  // heavy blocks dispatch first
    int h = bh & 15, b = bh >> 4;
    int q0 = qt * 32;
    int lr = lane & 15, lg = lane >> 4;
    size_t base = (size_t)b * SEQ;
    int cq = h * HDIM, ck = 1024 + h * HDIM, cv = 2048 + h * HDIM;

    // Q fragments in registers, pre-scaled by 1/sqrt(HD)
    f16x8 aq[2][2];
#pragma unroll
    for (int i = 0; i < 2; ++i)
#pragma unroll
        for (int kk = 0; kk < 2; ++kk) {
            f16x8 v = *(const f16x8*)(QKV + (base + q0 + i * 16 + lr) * LDQ + cq + kk * 32 + lg * 8);
#pragma unroll
            for (int e = 0; e < 8; ++e) v[e] = v[e] * (_Float16)0.125f;
            aq[i][kk] = v;
        }

    f32x4 cacc[2][4];
#pragma unroll
    for (int i = 0; i < 2; ++i)
#pragma unroll
        for (int j = 0; j < 4; ++j) cacc[i][j] = (f32x4){0.f, 0.f, 0.f, 0.f};
    float mrun[2][4], lrun[2][4];
#pragma unroll
    for (int i = 0; i < 2; ++i)
#pragma unroll
        for (int r = 0; r < 4; ++r) { mrun[i][r] = -1e30f; lrun[i][r] = 0.f; }

    int ntiles = q0 / 64 + 1;   // 64-wide K/V tiles needed for causal rows
    for (int kt = 0; kt < ntiles; ++kt) {
        int k0 = kt * 64;
        // stage V^T into LDS (scalar transposed writes, swizzled; 2-way = free)
        {
            const _Float16* vr = QKV + (base + k0 + lane) * LDQ + cv;
            int kslot = lane >> 3;
            int kb2 = (lane & 7) * 2;
#pragma unroll
            for (int part = 0; part < 8; ++part) {
                f16x8 v8 = *(const f16x8*)(vr + part * 8);
#pragma unroll
                for (int e = 0; e < 8; ++e) {
                    int d = part * 8 + e;
                    *(_Float16*)((char*)Vt + d * 128 + ((kslot ^ (d & 7)) << 4) + kb2) = v8[e];
                }
            }
        }
        // scores = Q K^T (K fragments straight from global, L2-hot)
        f32x4 sacc[2][4];
#pragma unroll
        for (int i = 0; i < 2; ++i)
#pragma unroll
            for (int j = 0; j < 4; ++j) sacc[i][j] = (f32x4){0.f, 0.f, 0.f, 0.f};
#pragma unroll
        for (int kk = 0; kk < 2; ++kk) {
            f16x8 bk[4];
#pragma unroll
            for (int j = 0; j < 4; ++j)
                bk[j] = *(const f16x8*)(QKV + (base + k0 + j * 16 + lr) * LDQ + ck + kk * 32 + lg * 8);
            __builtin_amdgcn_s_setprio(1);
#pragma unroll
            for (int i = 0; i < 2; ++i)
#pragma unroll
                for (int j = 0; j < 4; ++j)
                    sacc[i][j] = __builtin_amdgcn_mfma_f32_16x16x32_f16(aq[i][kk], bk[j], sacc[i][j], 0, 0, 0);
            __builtin_amdgcn_s_setprio(0);
        }
        // causal mask (last tile only; global coords)
        if (kt == ntiles - 1) {
#pragma unroll
            for (int i = 0; i < 2; ++i)
#pragma unroll
                for (int j = 0; j < 4; ++j)
#pragma unroll
                    for (int r = 0; r < 4; ++r) {
                        int qq = q0 + i * 16 + lg * 4 + r;
                        int kc = k0 + j * 16 + lr;
                        if (kc > qq) sacc[i][j][r] = -1e30f;
                    }
        }
        // online softmax (rows spread over 16 lanes)
#pragma unroll
        for (int i = 0; i < 2; ++i) {
            float mn[4], al[4];
#pragma unroll
            for (int r = 0; r < 4; ++r) {
                float tm = fmaxf(fmaxf(sacc[i][0][r], sacc[i][1][r]),
                                 fmaxf(sacc[i][2][r], sacc[i][3][r]));
#pragma unroll
                for (int msk = 1; msk < 16; msk <<= 1) tm = fmaxf(tm, __shfl_xor(tm, msk));
                float m2 = fmaxf(mrun[i][r], tm);
                al[r] = __expf(mrun[i][r] - m2);
                mrun[i][r] = m2;
                mn[r] = m2;
            }
#pragma unroll
            for (int jd = 0; jd < 4; ++jd)
#pragma unroll
                for (int r = 0; r < 4; ++r) cacc[i][jd][r] *= al[r];
#pragma unroll
            for (int r = 0; r < 4; ++r) {
                float ps = 0.f;
#pragma unroll
                for (int j = 0; j < 4; ++j) {
                    float p = __expf(sacc[i][j][r] - mn[r]);
                    sacc[i][j][r] = p;
                    ps += p;
                }
#pragma unroll
                for (int msk = 1; msk < 16; msk <<= 1) ps += __shfl_xor(ps, msk);
                lrun[i][r] = lrun[i][r] * al[r] + ps;
            }
        }
        // P -> LDS (f16, swizzled A-operand layout)
#pragma unroll
        for (int i = 0; i < 2; ++i)
#pragma unroll
            for (int j = 0; j < 4; ++j) {
                int kc = j * 16 + lr;
                int ks = kc >> 3;
                int kb = (kc & 7) * 2;
#pragma unroll
                for (int r = 0; r < 4; ++r) {
                    int qq = i * 16 + lg * 4 + r;
                    *(_Float16*)((char*)Ps + qq * 128 + ((ks ^ (qq & 7)) << 4) + kb) =
                        (_Float16)sacc[i][j][r];
                }
            }
        // PV accumulate (same-wave LDS RAW; in-order per-wave DS pipe)
#pragma unroll
        for (int kk = 0; kk < 2; ++kk) {
            f16x8 pa[2], bv[4];
#pragma unroll
            for (int i = 0; i < 2; ++i)   pa[i]  = ldsfrag(Ps, i * 16 + lr,  kk * 4 + lg);
#pragma unroll
            for (int jd = 0; jd < 4; ++jd) bv[jd] = ldsfrag(Vt, jd * 16 + lr, kk * 4 + lg);
            __builtin_amdgcn_s_setprio(1);
#pragma unroll
            for (int i = 0; i < 2; ++i)
#pragma unroll
                for (int jd = 0; jd < 4; ++jd)
                    cacc[i][jd] = __builtin_amdgcn_mfma_f32_16x16x32_f16(pa[i], bv[jd], cacc[i][jd], 0, 0, 0);
            __builtin_amdgcn_s_setprio(0);
        }
    }
    // normalize + write ctx in [b*S+s][h*64+d] layout
#pragma unroll
    for (int i = 0; i < 2; ++i)
#pragma unroll
        for (int jd = 0; jd < 4; ++jd)
#pragma unroll
            for (int r = 0; r < 4; ++r) {
                int qq = q0 + i * 16 + lg * 4 + r;
                int d = h * HDIM + jd * 16 + lr;
                Og[(base + qq) * DIM + d] = (_Float16)(cacc[i][jd][r] / lrun[i][r]);
            }
}

// ---------------------------------------------------------------------------
extern "C" void kernel_launch(void* const* d_in, const int* in_sizes, int n_in,
                              void* d_out, int out_size, void* d_ws, size_t ws_size,
                              hipStream_t stream) {
    const float* x    = (const float*)d_in[0];
    const float* WQ   = (const float*)d_in[1];
    const float* WK   = (const float*)d_in[2];
    const float* WV   = (const float*)d_in[3];
    const float* Wo   = (const float*)d_in[4];
    const float* bo   = (const float*)d_in[5];
    const float* W1   = (const float*)d_in[6];
    const float* b1   = (const float*)d_in[7];
    const float* W2   = (const float*)d_in[8];
    const float* b2   = (const float*)d_in[9];
    const float* ln1s = (const float*)d_in[10];
    const float* ln1b = (const float*)d_in[11];
    const float* ln2s = (const float*)d_in[12];
    const float* ln2b = (const float*)d_in[13];
    float* out = (float*)d_out;
    char* ws = (char*)d_ws;
    const size_t MB = 1024 * 1024;
    _Float16* WTqkv = (_Float16*)(ws + 0 * MB);   // [3072][1024] = 6MB
    _Float16* WTo   = (_Float16*)(ws + 6 * MB);
    _Float16* WT1   = (_Float16*)(ws + 8 * MB);   // [4096][1024]
    _Float16* WT2   = (_Float16*)(ws + 16 * MB);  // [1024][4096]
    _Float16* h1    = (_Float16*)(ws + 24 * MB);
    _Float16* qkvb  = (_Float16*)(ws + 32 * MB);  // [4096][3072] = 24MB
    _Float16* ctx   = (_Float16*)(ws + 56 * MB);
    _Float16* h2    = (_Float16*)(ws + 64 * MB);
    _Float16* ff1   = (_Float16*)(ws + 72 * MB);  // [4096][4096] = 32MB
    float*    x2    = (float*)   (ws + 104 * MB); // fp32 residual = 16MB

    dim3 tb(32, 8);
    k_tcvt3<<<dim3(32, 32, 3), tb, 0, stream>>>(WQ, WK, WV, WTqkv);
    k_tcvt<<<dim3(32, 32), tb, 0, stream>>>(Wo, WTo, 1024, 1024);
    k_tcvt<<<dim3(128, 32), tb, 0, stream>>>(W1, WT1, 1024, 4096);
    k_tcvt<<<dim3(32, 128), tb, 0, stream>>>(W2, WT2, 4096, 1024);

    k_ln<<<MTOT, 256, 0, stream>>>(x, ln1s, ln1b, h1);

    // fused QKV: [4096,1024] x [1024,3072] -> [4096,3072]  (24x32 tiles)
    k_gemm<0><<<dim3(768), 256, 0, stream>>>(h1, WTqkv, LDQ, DIM, 24, qkvb, nullptr);

    k_attn<<<dim3(2048), 64, 0, stream>>>(qkvb, ctx);

    // x2 = x + ctx @ Wo + bo   (512 blocks of 128x64)
    k_gemm64<<<dim3(512), 256, 0, stream>>>(ctx, WTo, DIM, DIM, x2, bo, x);

    k_ln<<<MTOT, 256, 0, stream>>>(x2, ln2s, ln2b, h2);

    // ff1 = gelu(h2 @ W1 + b1)  (32x32 tiles)
    k_gemm<1><<<dim3(1024), 256, 0, stream>>>(h2, WT1, DFF, DIM, 32, ff1, b1);

    // out = x2 + ff1 @ W2 + b2  (512 blocks of 128x64)
    k_gemm64<<<dim3(512), 256, 0, stream>>>(ff1, WT2, DIM, DFF, out, b2, x2);
}

// Round 10
// 235.163 us; speedup vs baseline: 1.0946x; 1.0346x over previous
//
#include <hip/hip_runtime.h>
#include <hip/hip_bf16.h>

#define DIM   1024
#define NHEAD 16
#define HDIM  64
#define BATCH 4
#define SEQ   1024
#define MTOT  (BATCH*SEQ)   // 4096
#define DFF   (4*DIM)       // 4096
#define LDQ   3072          // fused QKV row stride

typedef _Float16 f16x8 __attribute__((ext_vector_type(8)));
typedef _Float16 f16x4 __attribute__((ext_vector_type(4)));
typedef float    f32x4 __attribute__((ext_vector_type(4)));

// gelu(x) = 0.5x(1+tanh(z)) == x * sigmoid(2z), z = c(x + 0.044715 x^3).
__device__ __forceinline__ float geluf(float x) {
    float z2 = 1.5957691216057308f * (x + 0.044715f * x * x * x);  // 2*c*(...)
    return x * __builtin_amdgcn_rcpf(1.0f + __expf(-z2));
}

// Swizzled LDS byte offset for tiles with 64-f16 (128 B) rows, 8 slots of 16 B.
__device__ __forceinline__ int swz_off(int row, int slot) {
    return row * 128 + ((slot ^ (row & 7)) << 4);
}
__device__ __forceinline__ f16x8 ldsfrag(const _Float16* s, int row, int slot) {
    return *(const f16x8*)((const char*)s + swz_off(row, slot));
}

// Async global->LDS staging: linear LDS dest (wave-uniform base + lane*16),
// inverse-swizzled GLOBAL source so stored layout == swizzled layout (m173).
template <int NCHUNK>
__device__ __forceinline__ void stage_async(const _Float16* __restrict__ g, int ld,
                                            _Float16* s, int w, int lane) {
    int r_in = lane >> 3;               // 0..7 row within chunk
    int sslot = lane & 7;               // stored 16B slot
    int lslot = sslot ^ r_in;           // logical slot (row&7 == r_in)
#pragma unroll
    for (int q = 0; q < NCHUNK; ++q) {
        int chunk = w * NCHUNK + q;
        int row = chunk * 8 + r_in;
        const _Float16* gp = g + (size_t)row * ld + lslot * 8;
        _Float16* sp = s + chunk * 512;  // wave-uniform
        __builtin_amdgcn_global_load_lds(
            (const __attribute__((address_space(1))) void*)gp,
            (__attribute__((address_space(3))) void*)sp, 16, 0, 0);
    }
}

// ---------------- transpose + fp32->f16 convert:  src[K][N] -> dst[N][K] ----
__global__ __launch_bounds__(256) void k_tcvt(const float* __restrict__ src,
                                              _Float16* __restrict__ dst,
                                              int K, int N) {
    __shared__ float tile[32][33];
    int n0 = blockIdx.x * 32, k0 = blockIdx.y * 32;
    int tx = threadIdx.x, ty = threadIdx.y;
#pragma unroll
    for (int i = 0; i < 32; i += 8)
        tile[ty + i][tx] = src[(size_t)(k0 + ty + i) * N + (n0 + tx)];
    __syncthreads();
#pragma unroll
    for (int i = 0; i < 32; i += 8)
        dst[(size_t)(n0 + ty + i) * K + (k0 + tx)] = (_Float16)tile[tx][ty + i];
}

// three 1024x1024 transposes in one launch (z picks the source)
__global__ __launch_bounds__(256) void k_tcvt3(const float* __restrict__ s0,
                                               const float* __restrict__ s1,
                                               const float* __restrict__ s2,
                                               _Float16* __restrict__ dst) {
    __shared__ float tile[32][33];
    const float* src = blockIdx.z == 0 ? s0 : (blockIdx.z == 1 ? s1 : s2);
    _Float16* d = dst + (size_t)blockIdx.z * (1024 * 1024);
    int n0 = blockIdx.x * 32, k0 = blockIdx.y * 32;
    int tx = threadIdx.x, ty = threadIdx.y;
#pragma unroll
    for (int i = 0; i < 32; i += 8)
        tile[ty + i][tx] = src[(size_t)(k0 + ty + i) * 1024 + (n0 + tx)];
    __syncthreads();
#pragma unroll
    for (int i = 0; i < 32; i += 8)
        d[(size_t)(n0 + ty + i) * 1024 + (k0 + tx)] = (_Float16)tile[tx][ty + i];
}

// ---------------- LayerNorm (fp32 in -> f16 out), one block per row ---------
__global__ __launch_bounds__(256) void k_ln(const float* __restrict__ x,
                                            const float* __restrict__ sc,
                                            const float* __restrict__ sh,
                                            _Float16* __restrict__ out) {
    int row = blockIdx.x;
    int t = threadIdx.x;
    float4 v = ((const float4*)(x + (size_t)row * DIM))[t];
    float sum = v.x + v.y + v.z + v.w;
    float sq  = v.x * v.x + v.y * v.y + v.z * v.z + v.w * v.w;
#pragma unroll
    for (int m = 1; m < 64; m <<= 1) {
        sum += __shfl_xor(sum, m);
        sq  += __shfl_xor(sq, m);
    }
    __shared__ float rs[4], rq[4];
    int w = t >> 6;
    if ((t & 63) == 0) { rs[w] = sum; rq[w] = sq; }
    __syncthreads();
    sum = rs[0] + rs[1] + rs[2] + rs[3];
    sq  = rq[0] + rq[1] + rq[2] + rq[3];
    float mean = sum * (1.0f / DIM);
    float var  = sq * (1.0f / DIM) - mean * mean;
    float rstd = rsqrtf(var + 1e-5f);
    float4 s4 = ((const float4*)sc)[t];
    float4 b4 = ((const float4*)sh)[t];
    f16x4 o;
    o[0] = (_Float16)(s4.x * ((v.x - mean) * rstd) + b4.x);
    o[1] = (_Float16)(s4.y * ((v.y - mean) * rstd) + b4.y);
    o[2] = (_Float16)(s4.z * ((v.z - mean) * rstd) + b4.z);
    o[3] = (_Float16)(s4.w * ((v.w - mean) * rstd) + b4.w);
    ((f16x4*)(out + (size_t)row * DIM))[t] = o;
}

// ---------------- GEMM 128x128, BK=64, 2-phase pipelined, XCD-chunked -------
// (for N>=3072 outputs: QKV, FF1 — grids 768/1024 blocks)
// EPI: 0 = plain f16; 1 = +bias,gelu f16
template <int EPI>
__global__ __launch_bounds__(256) void k_gemm(const _Float16* __restrict__ A,
                                              const _Float16* __restrict__ BT,
                                              int N, int K, int gx,
                                              _Float16* __restrict__ Ch,
                                              const float* __restrict__ bias) {
    __shared__ _Float16 As[2][128 * 64];
    __shared__ _Float16 Bs[2][128 * 64];
    int t = threadIdx.x;
    int bid = blockIdx.x;
    int lin = (bid & 7) * ((int)gridDim.x >> 3) + (bid >> 3);
    int m0 = (lin / gx) * 128, n0 = (lin % gx) * 128;
    int lane = t & 63, w = t >> 6;
    int wm = (w >> 1) * 64, wn = (w & 1) * 64;
    int lr = lane & 15, lg = lane >> 4;
    f32x4 acc[4][4];
#pragma unroll
    for (int i = 0; i < 4; ++i)
#pragma unroll
        for (int j = 0; j < 4; ++j) acc[i][j] = (f32x4){0.f, 0.f, 0.f, 0.f};

    const _Float16* Ag = A  + (size_t)m0 * K;
    const _Float16* Bg = BT + (size_t)n0 * K;
    int nt = K / 64;
    stage_async<4>(Ag, K, As[0], w, lane);
    stage_async<4>(Bg, K, Bs[0], w, lane);
    __syncthreads();
    for (int tt = 0; tt < nt; ++tt) {
        int cur = tt & 1, nxt = cur ^ 1;
        if (tt + 1 < nt) {
            stage_async<4>(Ag + (tt + 1) * 64, K, As[nxt], w, lane);
            stage_async<4>(Bg + (tt + 1) * 64, K, Bs[nxt], w, lane);
        }
#pragma unroll
        for (int kk = 0; kk < 2; ++kk) {
            f16x8 a[4], b[4];
#pragma unroll
            for (int i = 0; i < 4; ++i) a[i] = ldsfrag(As[cur], wm + i * 16 + lr, kk * 4 + lg);
#pragma unroll
            for (int j = 0; j < 4; ++j) b[j] = ldsfrag(Bs[cur], wn + j * 16 + lr, kk * 4 + lg);
            __builtin_amdgcn_s_setprio(1);
#pragma unroll
            for (int i = 0; i < 4; ++i)
#pragma unroll
                for (int j = 0; j < 4; ++j)
                    acc[i][j] = __builtin_amdgcn_mfma_f32_16x16x32_f16(a[i], b[j], acc[i][j], 0, 0, 0);
            __builtin_amdgcn_s_setprio(0);
        }
        __syncthreads();   // drains next-tile loads; guards buffer reuse
    }
#pragma unroll
    for (int i = 0; i < 4; ++i) {
#pragma unroll
        for (int j = 0; j < 4; ++j) {
            int row = m0 + wm + i * 16 + lg * 4;
            int col = n0 + wn + j * 16 + lr;
#pragma unroll
            for (int r = 0; r < 4; ++r) {
                float v = acc[i][j][r];
                size_t idx = (size_t)(row + r) * N + col;
                if constexpr (EPI == 0) Ch[idx] = (_Float16)v;
                else                    Ch[idx] = (_Float16)geluf(v + bias[col]);
            }
        }
    }
}

// ---------------- GEMM 128x64 (N=1024: Wo, FF2), 3-buffer counted-vmcnt -----
// T4: per wave per tile = exactly 6 global_load_lds (A:4 + B:2). Loop invariant
// at iter entry: stages t (oldest 6) and t+1 (newest 6) outstanding. Wait
// vmcnt(6) -> t's loads landed (never drain to 0 mid-loop); raw s_barrier
// publishes cross-wave B rows; stage(t+2) issued after the barrier so the
// buffer it overwrites (read at iter t-1) is quiesced. 72 KB LDS -> 2 blk/CU.
__global__ __launch_bounds__(256) void k_gemm64(const _Float16* __restrict__ A,
                                                const _Float16* __restrict__ BT,
                                                int N, int K,
                                                float* __restrict__ Cf,
                                                const float* __restrict__ bias,
                                                const float* __restrict__ resid) {
    __shared__ _Float16 As[3][128 * 64];
    __shared__ _Float16 Bs[3][64 * 64];
    int t = threadIdx.x;
    int bid = blockIdx.x;
    int lin = (bid & 7) * ((int)gridDim.x >> 3) + (bid >> 3);
    int gx = N / 64;
    int m0 = (lin / gx) * 128, n0 = (lin % gx) * 64;
    int lane = t & 63, w = t >> 6;
    int wm = w * 32;
    int lr = lane & 15, lg = lane >> 4;
    f32x4 acc[2][4];
#pragma unroll
    for (int i = 0; i < 2; ++i)
#pragma unroll
        for (int j = 0; j < 4; ++j) acc[i][j] = (f32x4){0.f, 0.f, 0.f, 0.f};

    const _Float16* Ag = A  + (size_t)m0 * K;
    const _Float16* Bg = BT + (size_t)n0 * K;
    int nt = K / 64;
    // prologue: tiles 0 and 1 in flight (12 outstanding per wave)
    stage_async<4>(Ag, K, As[0], w, lane);
    stage_async<2>(Bg, K, Bs[0], w, lane);
    stage_async<4>(Ag + 64, K, As[1], w, lane);
    stage_async<2>(Bg + 64, K, Bs[1], w, lane);
    for (int tt = 0; tt < nt; ++tt) {
        if (tt + 1 < nt) asm volatile("s_waitcnt vmcnt(6)" ::: "memory");
        else             asm volatile("s_waitcnt vmcnt(0)" ::: "memory");
        __builtin_amdgcn_sched_barrier(0);
        __builtin_amdgcn_s_barrier();
        __builtin_amdgcn_sched_barrier(0);
        const _Float16* Ac = As[tt % 3];
        const _Float16* Bc = Bs[tt % 3];
#pragma unroll
        for (int kk = 0; kk < 2; ++kk) {
            f16x8 a[2], b[4];
#pragma unroll
            for (int i = 0; i < 2; ++i) a[i] = ldsfrag(Ac, wm + i * 16 + lr, kk * 4 + lg);
#pragma unroll
            for (int j = 0; j < 4; ++j) b[j] = ldsfrag(Bc, j * 16 + lr, kk * 4 + lg);
            __builtin_amdgcn_s_setprio(1);
#pragma unroll
            for (int i = 0; i < 2; ++i)
#pragma unroll
                for (int j = 0; j < 4; ++j)
                    acc[i][j] = __builtin_amdgcn_mfma_f32_16x16x32_f16(a[i], b[j], acc[i][j], 0, 0, 0);
            __builtin_amdgcn_s_setprio(0);
        }
        if (tt + 2 < nt) {
            int nb = (tt + 2) % 3;
            stage_async<4>(Ag + (tt + 2) * 64, K, As[nb], w, lane);
            stage_async<2>(Bg + (tt + 2) * 64, K, Bs[nb], w, lane);
        }
    }
#pragma unroll
    for (int i = 0; i < 2; ++i) {
#pragma unroll
        for (int j = 0; j < 4; ++j) {
            int row = m0 + wm + i * 16 + lg * 4;
            int col = n0 + j * 16 + lr;
#pragma unroll
            for (int r = 0; r < 4; ++r) {
                size_t idx = (size_t)(row + r) * N + col;
                Cf[idx] = acc[i][j][r] + bias[col] + resid[idx];
            }
        }
    }
}

// ---------------- Flash attention: 1 wave per (b, h, 32-row q-tile) ---------
// Barrier-free per-wave structure + LPT heavy-first 1D grid.
__global__ __launch_bounds__(64) void k_attn(const _Float16* __restrict__ QKV,
                                             _Float16* __restrict__ Og) {
    __shared__ _Float16 Vt[64 * 64];  // V^T [d][k], swizzled (8 KB)
    __shared__ _Float16 Ps[32 * 64];  // P[q][k], swizzled (4 KB)
    int lane = threadIdx.x;
    int id = blockIdx.x;
    int bh = id & 63;
    int qt = (SEQ / 32 - 1) - (id >> 6);  // heavy blocks dispatch first
    int h = bh & 15, b = bh >> 4;
    int q0 = qt * 32;
    int lr = lane & 15, lg = lane >> 4;
    size_t base = (size_t)b * SEQ;
    int cq = h * HDIM, ck = 1024 + h * HDIM, cv = 2048 + h * HDIM;

    // Q fragments in registers, pre-scaled by 1/sqrt(HD)
    f16x8 aq[2][2];
#pragma unroll
    for (int i = 0; i < 2; ++i)
#pragma unroll
        for (int kk = 0; kk < 2; ++kk) {
            f16x8 v = *(const f16x8*)(QKV + (base + q0 + i * 16 + lr) * LDQ + cq + kk * 32 + lg * 8);
#pragma unroll
            for (int e = 0; e < 8; ++e) v[e] = v[e] * (_Float16)0.125f;
            aq[i][kk] = v;
        }

    f32x4 cacc[2][4];
#pragma unroll
    for (int i = 0; i < 2; ++i)
#pragma unroll
        for (int j = 0; j < 4; ++j) cacc[i][j] = (f32x4){0.f, 0.f, 0.f, 0.f};
    float mrun[2][4], lrun[2][4];
#pragma unroll
    for (int i = 0; i < 2; ++i)
#pragma unroll
        for (int r = 0; r < 4; ++r) { mrun[i][r] = -1e30f; lrun[i][r] = 0.f; }

    int ntiles = q0 / 64 + 1;   // 64-wide K/V tiles needed for causal rows
    for (int kt = 0; kt < ntiles; ++kt) {
        int k0 = kt * 64;
        // stage V^T into LDS (scalar transposed writes, swizzled; 2-way = free)
        {
            const _Float16* vr = QKV + (base + k0 + lane) * LDQ + cv;
            int kslot = lane >> 3;
            int kb2 = (lane & 7) * 2;
#pragma unroll
            for (int part = 0; part < 8; ++part) {
                f16x8 v8 = *(const f16x8*)(vr + part * 8);
#pragma unroll
                for (int e = 0; e < 8; ++e) {
                    int d = part * 8 + e;
                    *(_Float16*)((char*)Vt + d * 128 + ((kslot ^ (d & 7)) << 4) + kb2) = v8[e];
                }
            }
        }
        // scores = Q K^T (K fragments straight from global, L2-hot)
        f32x4 sacc[2][4];
#pragma unroll
        for (int i = 0; i < 2; ++i)
#pragma unroll
            for (int j = 0; j < 4; ++j) sacc[i][j] = (f32x4){0.f, 0.f, 0.f, 0.f};
#pragma unroll
        for (int kk = 0; kk < 2; ++kk) {
            f16x8 bk[4];
#pragma unroll
            for (int j = 0; j < 4; ++j)
                bk[j] = *(const f16x8*)(QKV + (base + k0 + j * 16 + lr) * LDQ + ck + kk * 32 + lg * 8);
            __builtin_amdgcn_s_setprio(1);
#pragma unroll
            for (int i = 0; i < 2; ++i)
#pragma unroll
                for (int j = 0; j < 4; ++j)
                    sacc[i][j] = __builtin_amdgcn_mfma_f32_16x16x32_f16(aq[i][kk], bk[j], sacc[i][j], 0, 0, 0);
            __builtin_amdgcn_s_setprio(0);
        }
        // causal mask (last tile only; global coords)
        if (kt == ntiles - 1) {
#pragma unroll
            for (int i = 0; i < 2; ++i)
#pragma unroll
                for (int j = 0; j < 4; ++j)
#pragma unroll
                    for (int r = 0; r < 4; ++r) {
                        int qq = q0 + i * 16 + lg * 4 + r;
                        int kc = k0 + j * 16 + lr;
                        if (kc > qq) sacc[i][j][r] = -1e30f;
                    }
        }
        // online softmax (rows spread over 16 lanes)
#pragma unroll
        for (int i = 0; i < 2; ++i) {
            float mn[4], al[4];
#pragma unroll
            for (int r = 0; r < 4; ++r) {
                float tm = fmaxf(fmaxf(sacc[i][0][r], sacc[i][1][r]),
                                 fmaxf(sacc[i][2][r], sacc[i][3][r]));
#pragma unroll
                for (int msk = 1; msk < 16; msk <<= 1) tm = fmaxf(tm, __shfl_xor(tm, msk));
                float m2 = fmaxf(mrun[i][r], tm);
                al[r] = __expf(mrun[i][r] - m2);
                mrun[i][r] = m2;
                mn[r] = m2;
            }
#pragma unroll
            for (int jd = 0; jd < 4; ++jd)
#pragma unroll
                for (int r = 0; r < 4; ++r) cacc[i][jd][r] *= al[r];
#pragma unroll
            for (int r = 0; r < 4; ++r) {
                float ps = 0.f;
#pragma unroll
                for (int j = 0; j < 4; ++j) {
                    float p = __expf(sacc[i][j][r] - mn[r]);
                    sacc[i][j][r] = p;
                    ps += p;
                }
#pragma unroll
                for (int msk = 1; msk < 16; msk <<= 1) ps += __shfl_xor(ps, msk);
                lrun[i][r] = lrun[i][r] * al[r] + ps;
            }
        }
        // P -> LDS (f16, swizzled A-operand layout)
#pragma unroll
        for (int i = 0; i < 2; ++i)
#pragma unroll
            for (int j = 0; j < 4; ++j) {
                int kc = j * 16 + lr;
                int ks = kc >> 3;
                int kb = (kc & 7) * 2;
#pragma unroll
                for (int r = 0; r < 4; ++r) {
                    int qq = i * 16 + lg * 4 + r;
                    *(_Float16*)((char*)Ps + qq * 128 + ((ks ^ (qq & 7)) << 4) + kb) =
                        (_Float16)sacc[i][j][r];
                }
            }
        // PV accumulate (same-wave LDS RAW; in-order per-wave DS pipe)
#pragma unroll
        for (int kk = 0; kk < 2; ++kk) {
            f16x8 pa[2], bv[4];
#pragma unroll
            for (int i = 0; i < 2; ++i)   pa[i]  = ldsfrag(Ps, i * 16 + lr,  kk * 4 + lg);
#pragma unroll
            for (int jd = 0; jd < 4; ++jd) bv[jd] = ldsfrag(Vt, jd * 16 + lr, kk * 4 + lg);
            __builtin_amdgcn_s_setprio(1);
#pragma unroll
            for (int i = 0; i < 2; ++i)
#pragma unroll
                for (int jd = 0; jd < 4; ++jd)
                    cacc[i][jd] = __builtin_amdgcn_mfma_f32_16x16x32_f16(pa[i], bv[jd], cacc[i][jd], 0, 0, 0);
            __builtin_amdgcn_s_setprio(0);
        }
    }
    // normalize + write ctx in [b*S+s][h*64+d] layout
#pragma unroll
    for (int i = 0; i < 2; ++i)
#pragma unroll
        for (int jd = 0; jd < 4; ++jd)
#pragma unroll
            for (int r = 0; r < 4; ++r) {
                int qq = q0 + i * 16 + lg * 4 + r;
                int d = h * HDIM + jd * 16 + lr;
                Og[(base + qq) * DIM + d] = (_Float16)(cacc[i][jd][r] / lrun[i][r]);
            }
}

// ---------------------------------------------------------------------------
extern "C" void kernel_launch(void* const* d_in, const int* in_sizes, int n_in,
                              void* d_out, int out_size, void* d_ws, size_t ws_size,
                              hipStream_t stream) {
    const float* x    = (const float*)d_in[0];
    const float* WQ   = (const float*)d_in[1];
    const float* WK   = (const float*)d_in[2];
    const float* WV   = (const float*)d_in[3];
    const float* Wo   = (const float*)d_in[4];
    const float* bo   = (const float*)d_in[5];
    const float* W1   = (const float*)d_in[6];
    const float* b1   = (const float*)d_in[7];
    const float* W2   = (const float*)d_in[8];
    const float* b2   = (const float*)d_in[9];
    const float* ln1s = (const float*)d_in[10];
    const float* ln1b = (const float*)d_in[11];
    const float* ln2s = (const float*)d_in[12];
    const float* ln2b = (const float*)d_in[13];
    float* out = (float*)d_out;
    char* ws = (char*)d_ws;
    const size_t MB = 1024 * 1024;
    _Float16* WTqkv = (_Float16*)(ws + 0 * MB);   // [3072][1024] = 6MB
    _Float16* WTo   = (_Float16*)(ws + 6 * MB);
    _Float16* WT1   = (_Float16*)(ws + 8 * MB);   // [4096][1024]
    _Float16* WT2   = (_Float16*)(ws + 16 * MB);  // [1024][4096]
    _Float16* h1    = (_Float16*)(ws + 24 * MB);
    _Float16* qkvb  = (_Float16*)(ws + 32 * MB);  // [4096][3072] = 24MB
    _Float16* ctx   = (_Float16*)(ws + 56 * MB);
    _Float16* h2    = (_Float16*)(ws + 64 * MB);
    _Float16* ff1   = (_Float16*)(ws + 72 * MB);  // [4096][4096] = 32MB
    float*    x2    = (float*)   (ws + 104 * MB); // fp32 residual = 16MB

    dim3 tb(32, 8);
    k_tcvt3<<<dim3(32, 32, 3), tb, 0, stream>>>(WQ, WK, WV, WTqkv);
    k_tcvt<<<dim3(32, 32), tb, 0, stream>>>(Wo, WTo, 1024, 1024);
    k_tcvt<<<dim3(128, 32), tb, 0, stream>>>(W1, WT1, 1024, 4096);
    k_tcvt<<<dim3(32, 128), tb, 0, stream>>>(W2, WT2, 4096, 1024);

    k_ln<<<MTOT, 256, 0, stream>>>(x, ln1s, ln1b, h1);

    // fused QKV: [4096,1024] x [1024,3072] -> [4096,3072]  (24x32 tiles)
    k_gemm<0><<<dim3(768), 256, 0, stream>>>(h1, WTqkv, LDQ, DIM, 24, qkvb, nullptr);

    k_attn<<<dim3(2048), 64, 0, stream>>>(qkvb, ctx);

    // x2 = x + ctx @ Wo + bo   (512 blocks of 128x64, 3-deep pipeline)
    k_gemm64<<<dim3(512), 256, 0, stream>>>(ctx, WTo, DIM, DIM, x2, bo, x);

    k_ln<<<MTOT, 256, 0, stream>>>(x2, ln2s, ln2b, h2);

    // ff1 = gelu(h2 @ W1 + b1)  (32x32 tiles)
    k_gemm<1><<<dim3(1024), 256, 0, stream>>>(h2, WT1, DFF, DIM, 32, ff1, b1);

    // out = x2 + ff1 @ W2 + b2  (512 blocks of 128x64, 3-deep pipeline)
    k_gemm64<<<dim3(512), 256, 0, stream>>>(ff1, WT2, DIM, DFF, out, b2, x2);
}

// Round 11
// 235.115 us; speedup vs baseline: 1.0948x; 1.0002x over previous
//
#include <hip/hip_runtime.h>
#include <hip/hip_bf16.h>

#define DIM   1024
#define NHEAD 16
#define HDIM  64
#define BATCH 4
#define SEQ   1024
#define MTOT  (BATCH*SEQ)   // 4096
#define DFF   (4*DIM)       // 4096
#define LDQ   3072          // fused QKV row stride

typedef _Float16 f16x8 __attribute__((ext_vector_type(8)));
typedef _Float16 f16x4 __attribute__((ext_vector_type(4)));
typedef float    f32x4 __attribute__((ext_vector_type(4)));

// gelu(x) = 0.5x(1+tanh(z)) == x * sigmoid(2z), z = c(x + 0.044715 x^3).
__device__ __forceinline__ float geluf(float x) {
    float z2 = 1.5957691216057308f * (x + 0.044715f * x * x * x);  // 2*c*(...)
    return x * __builtin_amdgcn_rcpf(1.0f + __expf(-z2));
}

// Swizzled LDS byte offset for tiles with 64-f16 (128 B) rows, 8 slots of 16 B.
__device__ __forceinline__ int swz_off(int row, int slot) {
    return row * 128 + ((slot ^ (row & 7)) << 4);
}
__device__ __forceinline__ f16x8 ldsfrag(const _Float16* s, int row, int slot) {
    return *(const f16x8*)((const char*)s + swz_off(row, slot));
}

// Async global->LDS staging: linear LDS dest (wave-uniform base + lane*16),
// inverse-swizzled GLOBAL source so stored layout == swizzled layout (m173).
template <int NCHUNK>
__device__ __forceinline__ void stage_async(const _Float16* __restrict__ g, int ld,
                                            _Float16* s, int w, int lane) {
    int r_in = lane >> 3;               // 0..7 row within chunk
    int sslot = lane & 7;               // stored 16B slot
    int lslot = sslot ^ r_in;           // logical slot (row&7 == r_in)
#pragma unroll
    for (int q = 0; q < NCHUNK; ++q) {
        int chunk = w * NCHUNK + q;
        int row = chunk * 8 + r_in;
        const _Float16* gp = g + (size_t)row * ld + lslot * 8;
        _Float16* sp = s + chunk * 512;  // wave-uniform
        __builtin_amdgcn_global_load_lds(
            (const __attribute__((address_space(1))) void*)gp,
            (__attribute__((address_space(3))) void*)sp, 16, 0, 0);
    }
}

// ---------------- transpose + fp32->f16 convert:  src[K][N] -> dst[N][K] ----
__global__ __launch_bounds__(256) void k_tcvt(const float* __restrict__ src,
                                              _Float16* __restrict__ dst,
                                              int K, int N) {
    __shared__ float tile[32][33];
    int n0 = blockIdx.x * 32, k0 = blockIdx.y * 32;
    int tx = threadIdx.x, ty = threadIdx.y;
#pragma unroll
    for (int i = 0; i < 32; i += 8)
        tile[ty + i][tx] = src[(size_t)(k0 + ty + i) * N + (n0 + tx)];
    __syncthreads();
#pragma unroll
    for (int i = 0; i < 32; i += 8)
        dst[(size_t)(n0 + ty + i) * K + (k0 + tx)] = (_Float16)tile[tx][ty + i];
}

// three 1024x1024 transposes in one launch (z picks the source)
__global__ __launch_bounds__(256) void k_tcvt3(const float* __restrict__ s0,
                                               const float* __restrict__ s1,
                                               const float* __restrict__ s2,
                                               _Float16* __restrict__ dst) {
    __shared__ float tile[32][33];
    const float* src = blockIdx.z == 0 ? s0 : (blockIdx.z == 1 ? s1 : s2);
    _Float16* d = dst + (size_t)blockIdx.z * (1024 * 1024);
    int n0 = blockIdx.x * 32, k0 = blockIdx.y * 32;
    int tx = threadIdx.x, ty = threadIdx.y;
#pragma unroll
    for (int i = 0; i < 32; i += 8)
        tile[ty + i][tx] = src[(size_t)(k0 + ty + i) * 1024 + (n0 + tx)];
    __syncthreads();
#pragma unroll
    for (int i = 0; i < 32; i += 8)
        d[(size_t)(n0 + ty + i) * 1024 + (k0 + tx)] = (_Float16)tile[tx][ty + i];
}

// ---------------- LayerNorm (fp32 in -> f16 out), one block per row ---------
__global__ __launch_bounds__(256) void k_ln(const float* __restrict__ x,
                                            const float* __restrict__ sc,
                                            const float* __restrict__ sh,
                                            _Float16* __restrict__ out) {
    int row = blockIdx.x;
    int t = threadIdx.x;
    float4 v = ((const float4*)(x + (size_t)row * DIM))[t];
    float sum = v.x + v.y + v.z + v.w;
    float sq  = v.x * v.x + v.y * v.y + v.z * v.z + v.w * v.w;
#pragma unroll
    for (int m = 1; m < 64; m <<= 1) {
        sum += __shfl_xor(sum, m);
        sq  += __shfl_xor(sq, m);
    }
    __shared__ float rs[4], rq[4];
    int w = t >> 6;
    if ((t & 63) == 0) { rs[w] = sum; rq[w] = sq; }
    __syncthreads();
    sum = rs[0] + rs[1] + rs[2] + rs[3];
    sq  = rq[0] + rq[1] + rq[2] + rq[3];
    float mean = sum * (1.0f / DIM);
    float var  = sq * (1.0f / DIM) - mean * mean;
    float rstd = rsqrtf(var + 1e-5f);
    float4 s4 = ((const float4*)sc)[t];
    float4 b4 = ((const float4*)sh)[t];
    f16x4 o;
    o[0] = (_Float16)(s4.x * ((v.x - mean) * rstd) + b4.x);
    o[1] = (_Float16)(s4.y * ((v.y - mean) * rstd) + b4.y);
    o[2] = (_Float16)(s4.z * ((v.z - mean) * rstd) + b4.z);
    o[3] = (_Float16)(s4.w * ((v.w - mean) * rstd) + b4.w);
    ((f16x4*)(out + (size_t)row * DIM))[t] = o;
}

// ---------------- GEMM 128x128, BK=64, 2-phase pipelined, XCD-chunked -------
// (for N>=3072 outputs: QKV, FF1 — grids 768/1024 blocks)
// EPI: 0 = plain f16; 1 = +bias,gelu f16
template <int EPI>
__global__ __launch_bounds__(256) void k_gemm(const _Float16* __restrict__ A,
                                              const _Float16* __restrict__ BT,
                                              int N, int K, int gx,
                                              _Float16* __restrict__ Ch,
                                              const float* __restrict__ bias) {
    __shared__ _Float16 As[2][128 * 64];
    __shared__ _Float16 Bs[2][128 * 64];
    int t = threadIdx.x;
    int bid = blockIdx.x;
    int lin = (bid & 7) * ((int)gridDim.x >> 3) + (bid >> 3);
    int m0 = (lin / gx) * 128, n0 = (lin % gx) * 128;
    int lane = t & 63, w = t >> 6;
    int wm = (w >> 1) * 64, wn = (w & 1) * 64;
    int lr = lane & 15, lg = lane >> 4;
    f32x4 acc[4][4];
#pragma unroll
    for (int i = 0; i < 4; ++i)
#pragma unroll
        for (int j = 0; j < 4; ++j) acc[i][j] = (f32x4){0.f, 0.f, 0.f, 0.f};

    const _Float16* Ag = A  + (size_t)m0 * K;
    const _Float16* Bg = BT + (size_t)n0 * K;
    int nt = K / 64;
    stage_async<4>(Ag, K, As[0], w, lane);
    stage_async<4>(Bg, K, Bs[0], w, lane);
    __syncthreads();
    for (int tt = 0; tt < nt; ++tt) {
        int cur = tt & 1, nxt = cur ^ 1;
        if (tt + 1 < nt) {
            stage_async<4>(Ag + (tt + 1) * 64, K, As[nxt], w, lane);
            stage_async<4>(Bg + (tt + 1) * 64, K, Bs[nxt], w, lane);
        }
#pragma unroll
        for (int kk = 0; kk < 2; ++kk) {
            f16x8 a[4], b[4];
#pragma unroll
            for (int i = 0; i < 4; ++i) a[i] = ldsfrag(As[cur], wm + i * 16 + lr, kk * 4 + lg);
#pragma unroll
            for (int j = 0; j < 4; ++j) b[j] = ldsfrag(Bs[cur], wn + j * 16 + lr, kk * 4 + lg);
            __builtin_amdgcn_s_setprio(1);
#pragma unroll
            for (int i = 0; i < 4; ++i)
#pragma unroll
                for (int j = 0; j < 4; ++j)
                    acc[i][j] = __builtin_amdgcn_mfma_f32_16x16x32_f16(a[i], b[j], acc[i][j], 0, 0, 0);
            __builtin_amdgcn_s_setprio(0);
        }
        __syncthreads();   // drains next-tile loads; guards buffer reuse
    }
#pragma unroll
    for (int i = 0; i < 4; ++i) {
#pragma unroll
        for (int j = 0; j < 4; ++j) {
            int row = m0 + wm + i * 16 + lg * 4;
            int col = n0 + wn + j * 16 + lr;
#pragma unroll
            for (int r = 0; r < 4; ++r) {
                float v = acc[i][j][r];
                size_t idx = (size_t)(row + r) * N + col;
                if constexpr (EPI == 0) Ch[idx] = (_Float16)v;
                else                    Ch[idx] = (_Float16)geluf(v + bias[col]);
            }
        }
    }
}

// ---------------- GEMM 128x64 (N=1024: Wo, FF2), 3-buffer counted-vmcnt -----
__global__ __launch_bounds__(256) void k_gemm64(const _Float16* __restrict__ A,
                                                const _Float16* __restrict__ BT,
                                                int N, int K,
                                                float* __restrict__ Cf,
                                                const float* __restrict__ bias,
                                                const float* __restrict__ resid) {
    __shared__ _Float16 As[3][128 * 64];
    __shared__ _Float16 Bs[3][64 * 64];
    int t = threadIdx.x;
    int bid = blockIdx.x;
    int lin = (bid & 7) * ((int)gridDim.x >> 3) + (bid >> 3);
    int gx = N / 64;
    int m0 = (lin / gx) * 128, n0 = (lin % gx) * 64;
    int lane = t & 63, w = t >> 6;
    int wm = w * 32;
    int lr = lane & 15, lg = lane >> 4;
    f32x4 acc[2][4];
#pragma unroll
    for (int i = 0; i < 2; ++i)
#pragma unroll
        for (int j = 0; j < 4; ++j) acc[i][j] = (f32x4){0.f, 0.f, 0.f, 0.f};

    const _Float16* Ag = A  + (size_t)m0 * K;
    const _Float16* Bg = BT + (size_t)n0 * K;
    int nt = K / 64;
    // prologue: tiles 0 and 1 in flight (12 outstanding per wave)
    stage_async<4>(Ag, K, As[0], w, lane);
    stage_async<2>(Bg, K, Bs[0], w, lane);
    stage_async<4>(Ag + 64, K, As[1], w, lane);
    stage_async<2>(Bg + 64, K, Bs[1], w, lane);
    for (int tt = 0; tt < nt; ++tt) {
        if (tt + 1 < nt) asm volatile("s_waitcnt vmcnt(6)" ::: "memory");
        else             asm volatile("s_waitcnt vmcnt(0)" ::: "memory");
        __builtin_amdgcn_sched_barrier(0);
        __builtin_amdgcn_s_barrier();
        __builtin_amdgcn_sched_barrier(0);
        const _Float16* Ac = As[tt % 3];
        const _Float16* Bc = Bs[tt % 3];
#pragma unroll
        for (int kk = 0; kk < 2; ++kk) {
            f16x8 a[2], b[4];
#pragma unroll
            for (int i = 0; i < 2; ++i) a[i] = ldsfrag(Ac, wm + i * 16 + lr, kk * 4 + lg);
#pragma unroll
            for (int j = 0; j < 4; ++j) b[j] = ldsfrag(Bc, j * 16 + lr, kk * 4 + lg);
            __builtin_amdgcn_s_setprio(1);
#pragma unroll
            for (int i = 0; i < 2; ++i)
#pragma unroll
                for (int j = 0; j < 4; ++j)
                    acc[i][j] = __builtin_amdgcn_mfma_f32_16x16x32_f16(a[i], b[j], acc[i][j], 0, 0, 0);
            __builtin_amdgcn_s_setprio(0);
        }
        if (tt + 2 < nt) {
            int nb = (tt + 2) % 3;
            stage_async<4>(Ag + (tt + 2) * 64, K, As[nb], w, lane);
            stage_async<2>(Bg + (tt + 2) * 64, K, Bs[nb], w, lane);
        }
    }
#pragma unroll
    for (int i = 0; i < 2; ++i) {
#pragma unroll
        for (int j = 0; j < 4; ++j) {
            int row = m0 + wm + i * 16 + lg * 4;
            int col = n0 + j * 16 + lr;
#pragma unroll
            for (int r = 0; r < 4; ++r) {
                size_t idx = (size_t)(row + r) * N + col;
                Cf[idx] = acc[i][j][r] + bias[col] + resid[idx];
            }
        }
    }
}

// ---------------- Flash attention: 1 wave per (b, h, 32-row q-tile) ---------
// Barrier-free per-wave structure + LPT heavy-first 1D grid. V is NOT staged
// in LDS (m169: K/V L2-resident at S=1024 -> staging is pure overhead); PV
// B-fragments are read directly from global (per-lane strided 2B, L2-hot).
__global__ __launch_bounds__(64) void k_attn(const _Float16* __restrict__ QKV,
                                             _Float16* __restrict__ Og) {
    __shared__ _Float16 Ps[32 * 64];  // P[q][k], swizzled (4 KB)
    int lane = threadIdx.x;
    int id = blockIdx.x;
    int bh = id & 63;
    int qt = (SEQ / 32 - 1) - (id >> 6);  // heavy blocks dispatch first
    int h = bh & 15, b = bh >> 4;
    int q0 = qt * 32;
    int lr = lane & 15, lg = lane >> 4;
    size_t base = (size_t)b * SEQ;
    int cq = h * HDIM, ck = 1024 + h * HDIM, cv = 2048 + h * HDIM;

    // Q fragments in registers, pre-scaled by 1/sqrt(HD)
    f16x8 aq[2][2];
#pragma unroll
    for (int i = 0; i < 2; ++i)
#pragma unroll
        for (int kk = 0; kk < 2; ++kk) {
            f16x8 v = *(const f16x8*)(QKV + (base + q0 + i * 16 + lr) * LDQ + cq + kk * 32 + lg * 8);
#pragma unroll
            for (int e = 0; e < 8; ++e) v[e] = v[e] * (_Float16)0.125f;
            aq[i][kk] = v;
        }

    f32x4 cacc[2][4];
#pragma unroll
    for (int i = 0; i < 2; ++i)
#pragma unroll
        for (int j = 0; j < 4; ++j) cacc[i][j] = (f32x4){0.f, 0.f, 0.f, 0.f};
    float mrun[2][4], lrun[2][4];
#pragma unroll
    for (int i = 0; i < 2; ++i)
#pragma unroll
        for (int r = 0; r < 4; ++r) { mrun[i][r] = -1e30f; lrun[i][r] = 0.f; }

    int ntiles = q0 / 64 + 1;   // 64-wide K/V tiles needed for causal rows
    for (int kt = 0; kt < ntiles; ++kt) {
        int k0 = kt * 64;
        // scores = Q K^T (K fragments straight from global, L2-hot)
        f32x4 sacc[2][4];
#pragma unroll
        for (int i = 0; i < 2; ++i)
#pragma unroll
            for (int j = 0; j < 4; ++j) sacc[i][j] = (f32x4){0.f, 0.f, 0.f, 0.f};
#pragma unroll
        for (int kk = 0; kk < 2; ++kk) {
            f16x8 bk[4];
#pragma unroll
            for (int j = 0; j < 4; ++j)
                bk[j] = *(const f16x8*)(QKV + (base + k0 + j * 16 + lr) * LDQ + ck + kk * 32 + lg * 8);
            __builtin_amdgcn_s_setprio(1);
#pragma unroll
            for (int i = 0; i < 2; ++i)
#pragma unroll
                for (int j = 0; j < 4; ++j)
                    sacc[i][j] = __builtin_amdgcn_mfma_f32_16x16x32_f16(aq[i][kk], bk[j], sacc[i][j], 0, 0, 0);
            __builtin_amdgcn_s_setprio(0);
        }
        // causal mask (last tile only; global coords)
        if (kt == ntiles - 1) {
#pragma unroll
            for (int i = 0; i < 2; ++i)
#pragma unroll
                for (int j = 0; j < 4; ++j)
#pragma unroll
                    for (int r = 0; r < 4; ++r) {
                        int qq = q0 + i * 16 + lg * 4 + r;
                        int kc = k0 + j * 16 + lr;
                        if (kc > qq) sacc[i][j][r] = -1e30f;
                    }
        }
        // online softmax (rows spread over 16 lanes)
#pragma unroll
        for (int i = 0; i < 2; ++i) {
            float mn[4], al[4];
#pragma unroll
            for (int r = 0; r < 4; ++r) {
                float tm = fmaxf(fmaxf(sacc[i][0][r], sacc[i][1][r]),
                                 fmaxf(sacc[i][2][r], sacc[i][3][r]));
#pragma unroll
                for (int msk = 1; msk < 16; msk <<= 1) tm = fmaxf(tm, __shfl_xor(tm, msk));
                float m2 = fmaxf(mrun[i][r], tm);
                al[r] = __expf(mrun[i][r] - m2);
                mrun[i][r] = m2;
                mn[r] = m2;
            }
#pragma unroll
            for (int jd = 0; jd < 4; ++jd)
#pragma unroll
                for (int r = 0; r < 4; ++r) cacc[i][jd][r] *= al[r];
#pragma unroll
            for (int r = 0; r < 4; ++r) {
                float ps = 0.f;
#pragma unroll
                for (int j = 0; j < 4; ++j) {
                    float p = __expf(sacc[i][j][r] - mn[r]);
                    sacc[i][j][r] = p;
                    ps += p;
                }
#pragma unroll
                for (int msk = 1; msk < 16; msk <<= 1) ps += __shfl_xor(ps, msk);
                lrun[i][r] = lrun[i][r] * al[r] + ps;
            }
        }
        // P -> LDS (f16, swizzled A-operand layout)
#pragma unroll
        for (int i = 0; i < 2; ++i)
#pragma unroll
            for (int j = 0; j < 4; ++j) {
                int kc = j * 16 + lr;
                int ks = kc >> 3;
                int kb = (kc & 7) * 2;
#pragma unroll
                for (int r = 0; r < 4; ++r) {
                    int qq = i * 16 + lg * 4 + r;
                    *(_Float16*)((char*)Ps + qq * 128 + ((ks ^ (qq & 7)) << 4) + kb) =
                        (_Float16)sacc[i][j][r];
                }
            }
        // PV accumulate; V B-fragments direct from global:
        // bv[jd][e] = V[k0 + kk*32 + lg*8 + e][cv + jd*16 + lr]
        {
            const _Float16* vb = QKV + (base + k0) * LDQ + cv;
#pragma unroll
            for (int kk = 0; kk < 2; ++kk) {
                f16x8 pa[2], bv[4];
#pragma unroll
                for (int i = 0; i < 2; ++i) pa[i] = ldsfrag(Ps, i * 16 + lr, kk * 4 + lg);
                const _Float16* vk = vb + (size_t)(kk * 32 + lg * 8) * LDQ + lr;
#pragma unroll
                for (int jd = 0; jd < 4; ++jd)
#pragma unroll
                    for (int e = 0; e < 8; ++e)
                        bv[jd][e] = vk[(size_t)e * LDQ + jd * 16];
                __builtin_amdgcn_s_setprio(1);
#pragma unroll
                for (int i = 0; i < 2; ++i)
#pragma unroll
                    for (int jd = 0; jd < 4; ++jd)
                        cacc[i][jd] = __builtin_amdgcn_mfma_f32_16x16x32_f16(pa[i], bv[jd], cacc[i][jd], 0, 0, 0);
                __builtin_amdgcn_s_setprio(0);
            }
        }
    }
    // normalize + write ctx in [b*S+s][h*64+d] layout
#pragma unroll
    for (int i = 0; i < 2; ++i)
#pragma unroll
        for (int jd = 0; jd < 4; ++jd)
#pragma unroll
            for (int r = 0; r < 4; ++r) {
                int qq = q0 + i * 16 + lg * 4 + r;
                int d = h * HDIM + jd * 16 + lr;
                Og[(base + qq) * DIM + d] = (_Float16)(cacc[i][jd][r] / lrun[i][r]);
            }
}

// ---------------------------------------------------------------------------
extern "C" void kernel_launch(void* const* d_in, const int* in_sizes, int n_in,
                              void* d_out, int out_size, void* d_ws, size_t ws_size,
                              hipStream_t stream) {
    const float* x    = (const float*)d_in[0];
    const float* WQ   = (const float*)d_in[1];
    const float* WK   = (const float*)d_in[2];
    const float* WV   = (const float*)d_in[3];
    const float* Wo   = (const float*)d_in[4];
    const float* bo   = (const float*)d_in[5];
    const float* W1   = (const float*)d_in[6];
    const float* b1   = (const float*)d_in[7];
    const float* W2   = (const float*)d_in[8];
    const float* b2   = (const float*)d_in[9];
    const float* ln1s = (const float*)d_in[10];
    const float* ln1b = (const float*)d_in[11];
    const float* ln2s = (const float*)d_in[12];
    const float* ln2b = (const float*)d_in[13];
    float* out = (float*)d_out;
    char* ws = (char*)d_ws;
    const size_t MB = 1024 * 1024;
    _Float16* WTqkv = (_Float16*)(ws + 0 * MB);   // [3072][1024] = 6MB
    _Float16* WTo   = (_Float16*)(ws + 6 * MB);
    _Float16* WT1   = (_Float16*)(ws + 8 * MB);   // [4096][1024]
    _Float16* WT2   = (_Float16*)(ws + 16 * MB);  // [1024][4096]
    _Float16* h1    = (_Float16*)(ws + 24 * MB);
    _Float16* qkvb  = (_Float16*)(ws + 32 * MB);  // [4096][3072] = 24MB
    _Float16* ctx   = (_Float16*)(ws + 56 * MB);
    _Float16* h2    = (_Float16*)(ws + 64 * MB);
    _Float16* ff1   = (_Float16*)(ws + 72 * MB);  // [4096][4096] = 32MB
    float*    x2    = (float*)   (ws + 104 * MB); // fp32 residual = 16MB

    dim3 tb(32, 8);
    k_tcvt3<<<dim3(32, 32, 3), tb, 0, stream>>>(WQ, WK, WV, WTqkv);
    k_tcvt<<<dim3(32, 32), tb, 0, stream>>>(Wo, WTo, 1024, 1024);
    k_tcvt<<<dim3(128, 32), tb, 0, stream>>>(W1, WT1, 1024, 4096);
    k_tcvt<<<dim3(32, 128), tb, 0, stream>>>(W2, WT2, 4096, 1024);

    k_ln<<<MTOT, 256, 0, stream>>>(x, ln1s, ln1b, h1);

    // fused QKV: [4096,1024] x [1024,3072] -> [4096,3072]  (24x32 tiles)
    k_gemm<0><<<dim3(768), 256, 0, stream>>>(h1, WTqkv, LDQ, DIM, 24, qkvb, nullptr);

    k_attn<<<dim3(2048), 64, 0, stream>>>(qkvb, ctx);

    // x2 = x + ctx @ Wo + bo   (512 blocks of 128x64, 3-deep pipeline)
    k_gemm64<<<dim3(512), 256, 0, stream>>>(ctx, WTo, DIM, DIM, x2, bo, x);

    k_ln<<<MTOT, 256, 0, stream>>>(x2, ln2s, ln2b, h2);

    // ff1 = gelu(h2 @ W1 + b1)  (32x32 tiles)
    k_gemm<1><<<dim3(1024), 256, 0, stream>>>(h2, WT1, DFF, DIM, 32, ff1, b1);

    // out = x2 + ff1 @ W2 + b2  (512 blocks of 128x64, 3-deep pipeline)
    k_gemm64<<<dim3(512), 256, 0, stream>>>(ff1, WT2, DIM, DFF, out, b2, x2);
}

// Round 12
// 233.873 us; speedup vs baseline: 1.1006x; 1.0053x over previous
//
#include <hip/hip_runtime.h>
#include <hip/hip_bf16.h>

#define DIM   1024
#define NHEAD 16
#define HDIM  64
#define BATCH 4
#define SEQ   1024
#define MTOT  (BATCH*SEQ)   // 4096
#define DFF   (4*DIM)       // 4096
#define LDQ   3072          // fused QKV row stride

typedef _Float16 f16x8 __attribute__((ext_vector_type(8)));
typedef _Float16 f16x4 __attribute__((ext_vector_type(4)));
typedef float    f32x4 __attribute__((ext_vector_type(4)));

// gelu(x) = 0.5x(1+tanh(z)) == x * sigmoid(2z), z = c(x + 0.044715 x^3).
__device__ __forceinline__ float geluf(float x) {
    float z2 = 1.5957691216057308f * (x + 0.044715f * x * x * x);  // 2*c*(...)
    return x * __builtin_amdgcn_rcpf(1.0f + __expf(-z2));
}

// Swizzled LDS byte offset for tiles with 64-f16 (128 B) rows, 8 slots of 16 B.
__device__ __forceinline__ int swz_off(int row, int slot) {
    return row * 128 + ((slot ^ (row & 7)) << 4);
}
__device__ __forceinline__ f16x8 ldsfrag(const _Float16* s, int row, int slot) {
    return *(const f16x8*)((const char*)s + swz_off(row, slot));
}

// Async global->LDS staging: linear LDS dest (wave-uniform base + lane*16),
// inverse-swizzled GLOBAL source so stored layout == swizzled layout (m173).
template <int NCHUNK>
__device__ __forceinline__ void stage_async(const _Float16* __restrict__ g, int ld,
                                            _Float16* s, int w, int lane) {
    int r_in = lane >> 3;               // 0..7 row within chunk
    int sslot = lane & 7;               // stored 16B slot
    int lslot = sslot ^ r_in;           // logical slot (row&7 == r_in)
#pragma unroll
    for (int q = 0; q < NCHUNK; ++q) {
        int chunk = w * NCHUNK + q;
        int row = chunk * 8 + r_in;
        const _Float16* gp = g + (size_t)row * ld + lslot * 8;
        _Float16* sp = s + chunk * 512;  // wave-uniform
        __builtin_amdgcn_global_load_lds(
            (const __attribute__((address_space(1))) void*)gp,
            (__attribute__((address_space(3))) void*)sp, 16, 0, 0);
    }
}

// ---------------- transpose + fp32->f16 convert:  src[K][N] -> dst[N][K] ----
__global__ __launch_bounds__(256) void k_tcvt(const float* __restrict__ src,
                                              _Float16* __restrict__ dst,
                                              int K, int N) {
    __shared__ float tile[32][33];
    int n0 = blockIdx.x * 32, k0 = blockIdx.y * 32;
    int tx = threadIdx.x, ty = threadIdx.y;
#pragma unroll
    for (int i = 0; i < 32; i += 8)
        tile[ty + i][tx] = src[(size_t)(k0 + ty + i) * N + (n0 + tx)];
    __syncthreads();
#pragma unroll
    for (int i = 0; i < 32; i += 8)
        dst[(size_t)(n0 + ty + i) * K + (k0 + tx)] = (_Float16)tile[tx][ty + i];
}

// three 1024x1024 transposes in one launch (z picks the source)
__global__ __launch_bounds__(256) void k_tcvt3(const float* __restrict__ s0,
                                               const float* __restrict__ s1,
                                               const float* __restrict__ s2,
                                               _Float16* __restrict__ dst) {
    __shared__ float tile[32][33];
    const float* src = blockIdx.z == 0 ? s0 : (blockIdx.z == 1 ? s1 : s2);
    _Float16* d = dst + (size_t)blockIdx.z * (1024 * 1024);
    int n0 = blockIdx.x * 32, k0 = blockIdx.y * 32;
    int tx = threadIdx.x, ty = threadIdx.y;
#pragma unroll
    for (int i = 0; i < 32; i += 8)
        tile[ty + i][tx] = src[(size_t)(k0 + ty + i) * 1024 + (n0 + tx)];
    __syncthreads();
#pragma unroll
    for (int i = 0; i < 32; i += 8)
        d[(size_t)(n0 + ty + i) * 1024 + (k0 + tx)] = (_Float16)tile[tx][ty + i];
}

// ---------------- LayerNorm (fp32 in -> f16 out), one block per row ---------
__global__ __launch_bounds__(256) void k_ln(const float* __restrict__ x,
                                            const float* __restrict__ sc,
                                            const float* __restrict__ sh,
                                            _Float16* __restrict__ out) {
    int row = blockIdx.x;
    int t = threadIdx.x;
    float4 v = ((const float4*)(x + (size_t)row * DIM))[t];
    float sum = v.x + v.y + v.z + v.w;
    float sq  = v.x * v.x + v.y * v.y + v.z * v.z + v.w * v.w;
#pragma unroll
    for (int m = 1; m < 64; m <<= 1) {
        sum += __shfl_xor(sum, m);
        sq  += __shfl_xor(sq, m);
    }
    __shared__ float rs[4], rq[4];
    int w = t >> 6;
    if ((t & 63) == 0) { rs[w] = sum; rq[w] = sq; }
    __syncthreads();
    sum = rs[0] + rs[1] + rs[2] + rs[3];
    sq  = rq[0] + rq[1] + rq[2] + rq[3];
    float mean = sum * (1.0f / DIM);
    float var  = sq * (1.0f / DIM) - mean * mean;
    float rstd = rsqrtf(var + 1e-5f);
    float4 s4 = ((const float4*)sc)[t];
    float4 b4 = ((const float4*)sh)[t];
    f16x4 o;
    o[0] = (_Float16)(s4.x * ((v.x - mean) * rstd) + b4.x);
    o[1] = (_Float16)(s4.y * ((v.y - mean) * rstd) + b4.y);
    o[2] = (_Float16)(s4.z * ((v.z - mean) * rstd) + b4.z);
    o[3] = (_Float16)(s4.w * ((v.w - mean) * rstd) + b4.w);
    ((f16x4*)(out + (size_t)row * DIM))[t] = o;
}

// ---------------- GEMM 128x128, BK=64, 2-phase pipelined, XCD-chunked -------
// (for N>=3072 outputs: QKV, FF1 — grids 768/1024 blocks)
// EPI: 0 = plain f16; 1 = +bias,gelu f16
template <int EPI>
__global__ __launch_bounds__(256) void k_gemm(const _Float16* __restrict__ A,
                                              const _Float16* __restrict__ BT,
                                              int N, int K, int gx,
                                              _Float16* __restrict__ Ch,
                                              const float* __restrict__ bias) {
    __shared__ _Float16 As[2][128 * 64];
    __shared__ _Float16 Bs[2][128 * 64];
    int t = threadIdx.x;
    int bid = blockIdx.x;
    int lin = (bid & 7) * ((int)gridDim.x >> 3) + (bid >> 3);
    int m0 = (lin / gx) * 128, n0 = (lin % gx) * 128;
    int lane = t & 63, w = t >> 6;
    int wm = (w >> 1) * 64, wn = (w & 1) * 64;
    int lr = lane & 15, lg = lane >> 4;
    f32x4 acc[4][4];
#pragma unroll
    for (int i = 0; i < 4; ++i)
#pragma unroll
        for (int j = 0; j < 4; ++j) acc[i][j] = (f32x4){0.f, 0.f, 0.f, 0.f};

    const _Float16* Ag = A  + (size_t)m0 * K;
    const _Float16* Bg = BT + (size_t)n0 * K;
    int nt = K / 64;
    stage_async<4>(Ag, K, As[0], w, lane);
    stage_async<4>(Bg, K, Bs[0], w, lane);
    __syncthreads();
    for (int tt = 0; tt < nt; ++tt) {
        int cur = tt & 1, nxt = cur ^ 1;
        if (tt + 1 < nt) {
            stage_async<4>(Ag + (tt + 1) * 64, K, As[nxt], w, lane);
            stage_async<4>(Bg + (tt + 1) * 64, K, Bs[nxt], w, lane);
        }
#pragma unroll
        for (int kk = 0; kk < 2; ++kk) {
            f16x8 a[4], b[4];
#pragma unroll
            for (int i = 0; i < 4; ++i) a[i] = ldsfrag(As[cur], wm + i * 16 + lr, kk * 4 + lg);
#pragma unroll
            for (int j = 0; j < 4; ++j) b[j] = ldsfrag(Bs[cur], wn + j * 16 + lr, kk * 4 + lg);
            __builtin_amdgcn_s_setprio(1);
#pragma unroll
            for (int i = 0; i < 4; ++i)
#pragma unroll
                for (int j = 0; j < 4; ++j)
                    acc[i][j] = __builtin_amdgcn_mfma_f32_16x16x32_f16(a[i], b[j], acc[i][j], 0, 0, 0);
            __builtin_amdgcn_s_setprio(0);
        }
        __syncthreads();   // drains next-tile loads; guards buffer reuse
    }
#pragma unroll
    for (int i = 0; i < 4; ++i) {
#pragma unroll
        for (int j = 0; j < 4; ++j) {
            int row = m0 + wm + i * 16 + lg * 4;
            int col = n0 + wn + j * 16 + lr;
#pragma unroll
            for (int r = 0; r < 4; ++r) {
                float v = acc[i][j][r];
                size_t idx = (size_t)(row + r) * N + col;
                if constexpr (EPI == 0) Ch[idx] = (_Float16)v;
                else                    Ch[idx] = (_Float16)geluf(v + bias[col]);
            }
        }
    }
}

// ---------------- GEMM 128x64 (N=1024: Wo, FF2), 3-buffer counted-vmcnt -----
__global__ __launch_bounds__(256) void k_gemm64(const _Float16* __restrict__ A,
                                                const _Float16* __restrict__ BT,
                                                int N, int K,
                                                float* __restrict__ Cf,
                                                const float* __restrict__ bias,
                                                const float* __restrict__ resid) {
    __shared__ _Float16 As[3][128 * 64];
    __shared__ _Float16 Bs[3][64 * 64];
    int t = threadIdx.x;
    int bid = blockIdx.x;
    int lin = (bid & 7) * ((int)gridDim.x >> 3) + (bid >> 3);
    int gx = N / 64;
    int m0 = (lin / gx) * 128, n0 = (lin % gx) * 64;
    int lane = t & 63, w = t >> 6;
    int wm = w * 32;
    int lr = lane & 15, lg = lane >> 4;
    f32x4 acc[2][4];
#pragma unroll
    for (int i = 0; i < 2; ++i)
#pragma unroll
        for (int j = 0; j < 4; ++j) acc[i][j] = (f32x4){0.f, 0.f, 0.f, 0.f};

    const _Float16* Ag = A  + (size_t)m0 * K;
    const _Float16* Bg = BT + (size_t)n0 * K;
    int nt = K / 64;
    // prologue: tiles 0 and 1 in flight (12 outstanding per wave)
    stage_async<4>(Ag, K, As[0], w, lane);
    stage_async<2>(Bg, K, Bs[0], w, lane);
    stage_async<4>(Ag + 64, K, As[1], w, lane);
    stage_async<2>(Bg + 64, K, Bs[1], w, lane);
    for (int tt = 0; tt < nt; ++tt) {
        if (tt + 1 < nt) asm volatile("s_waitcnt vmcnt(6)" ::: "memory");
        else             asm volatile("s_waitcnt vmcnt(0)" ::: "memory");
        __builtin_amdgcn_sched_barrier(0);
        __builtin_amdgcn_s_barrier();
        __builtin_amdgcn_sched_barrier(0);
        const _Float16* Ac = As[tt % 3];
        const _Float16* Bc = Bs[tt % 3];
#pragma unroll
        for (int kk = 0; kk < 2; ++kk) {
            f16x8 a[2], b[4];
#pragma unroll
            for (int i = 0; i < 2; ++i) a[i] = ldsfrag(Ac, wm + i * 16 + lr, kk * 4 + lg);
#pragma unroll
            for (int j = 0; j < 4; ++j) b[j] = ldsfrag(Bc, j * 16 + lr, kk * 4 + lg);
            __builtin_amdgcn_s_setprio(1);
#pragma unroll
            for (int i = 0; i < 2; ++i)
#pragma unroll
                for (int j = 0; j < 4; ++j)
                    acc[i][j] = __builtin_amdgcn_mfma_f32_16x16x32_f16(a[i], b[j], acc[i][j], 0, 0, 0);
            __builtin_amdgcn_s_setprio(0);
        }
        if (tt + 2 < nt) {
            int nb = (tt + 2) % 3;
            stage_async<4>(Ag + (tt + 2) * 64, K, As[nb], w, lane);
            stage_async<2>(Bg + (tt + 2) * 64, K, Bs[nb], w, lane);
        }
    }
#pragma unroll
    for (int i = 0; i < 2; ++i) {
#pragma unroll
        for (int j = 0; j < 4; ++j) {
            int row = m0 + wm + i * 16 + lg * 4;
            int col = n0 + j * 16 + lr;
#pragma unroll
            for (int r = 0; r < 4; ++r) {
                size_t idx = (size_t)(row + r) * N + col;
                Cf[idx] = acc[i][j][r] + bias[col] + resid[idx];
            }
        }
    }
}

// ---------------- Flash attention: 16-row q-tiles, 4 independent waves/block
// QBLK=16 -> 4096 q-tiles; 4 waves packed per 256-thread block (no barriers,
// LDS partitioned per wave). Consecutive LPT ids -> all 4 waves in a block
// share the same qt (identical work -> block drains as a unit). 1024 blocks
// = 4 blocks/CU x 4 waves = 16 waves/CU static (4/SIMD) for latency hiding.
// V is not LDS-staged (L2-hot, m169); K/V frags direct from global.
__global__ __launch_bounds__(256) void k_attn(const _Float16* __restrict__ QKV,
                                              _Float16* __restrict__ Og) {
    __shared__ _Float16 PsA[4][16 * 64];  // per-wave P[q][k], swizzled (2 KB)
    int t = threadIdx.x;
    int lane = t & 63, w = t >> 6;
    int id = blockIdx.x * 4 + w;          // global tile id
    int bh = id & 63;
    int qt = 63 - (id >> 6);              // heavy tiles dispatch first (LPT)
    int h = bh & 15, b = bh >> 4;
    int q0 = qt * 16;
    int lr = lane & 15, lg = lane >> 4;
    size_t base = (size_t)b * SEQ;
    int cq = h * HDIM, ck = 1024 + h * HDIM, cv = 2048 + h * HDIM;
    _Float16* Ps = &PsA[w][0];

    // Q fragments (16 rows), pre-scaled by 1/sqrt(HD)
    f16x8 aq[2];
#pragma unroll
    for (int kk = 0; kk < 2; ++kk) {
        f16x8 v = *(const f16x8*)(QKV + (base + q0 + lr) * LDQ + cq + kk * 32 + lg * 8);
#pragma unroll
        for (int e = 0; e < 8; ++e) v[e] = v[e] * (_Float16)0.125f;
        aq[kk] = v;
    }

    f32x4 cacc[4];
#pragma unroll
    for (int j = 0; j < 4; ++j) cacc[j] = (f32x4){0.f, 0.f, 0.f, 0.f};
    float mrun[4], lrun[4];
#pragma unroll
    for (int r = 0; r < 4; ++r) { mrun[r] = -1e30f; lrun[r] = 0.f; }

    int ntiles = q0 / 64 + 1;   // 64-wide K/V tiles needed for causal rows
    for (int kt = 0; kt < ntiles; ++kt) {
        int k0 = kt * 64;
        // scores = Q K^T (K fragments straight from global, L2-hot)
        f32x4 sacc[4];
#pragma unroll
        for (int j = 0; j < 4; ++j) sacc[j] = (f32x4){0.f, 0.f, 0.f, 0.f};
#pragma unroll
        for (int kk = 0; kk < 2; ++kk) {
            f16x8 bk[4];
#pragma unroll
            for (int j = 0; j < 4; ++j)
                bk[j] = *(const f16x8*)(QKV + (base + k0 + j * 16 + lr) * LDQ + ck + kk * 32 + lg * 8);
            __builtin_amdgcn_s_setprio(1);
#pragma unroll
            for (int j = 0; j < 4; ++j)
                sacc[j] = __builtin_amdgcn_mfma_f32_16x16x32_f16(aq[kk], bk[j], sacc[j], 0, 0, 0);
            __builtin_amdgcn_s_setprio(0);
        }
        // causal mask (last tile only; global coords)
        if (kt == ntiles - 1) {
#pragma unroll
            for (int j = 0; j < 4; ++j)
#pragma unroll
                for (int r = 0; r < 4; ++r) {
                    int qq = q0 + lg * 4 + r;
                    int kc = k0 + j * 16 + lr;
                    if (kc > qq) sacc[j][r] = -1e30f;
                }
        }
        // online softmax (rows spread over 16 lanes)
        {
            float mn[4], al[4];
#pragma unroll
            for (int r = 0; r < 4; ++r) {
                float tm = fmaxf(fmaxf(sacc[0][r], sacc[1][r]),
                                 fmaxf(sacc[2][r], sacc[3][r]));
#pragma unroll
                for (int msk = 1; msk < 16; msk <<= 1) tm = fmaxf(tm, __shfl_xor(tm, msk));
                float m2 = fmaxf(mrun[r], tm);
                al[r] = __expf(mrun[r] - m2);
                mrun[r] = m2;
                mn[r] = m2;
            }
#pragma unroll
            for (int jd = 0; jd < 4; ++jd)
#pragma unroll
                for (int r = 0; r < 4; ++r) cacc[jd][r] *= al[r];
#pragma unroll
            for (int r = 0; r < 4; ++r) {
                float ps = 0.f;
#pragma unroll
                for (int j = 0; j < 4; ++j) {
                    float p = __expf(sacc[j][r] - mn[r]);
                    sacc[j][r] = p;
                    ps += p;
                }
#pragma unroll
                for (int msk = 1; msk < 16; msk <<= 1) ps += __shfl_xor(ps, msk);
                lrun[r] = lrun[r] * al[r] + ps;
            }
        }
        // P -> per-wave LDS (f16, swizzled A-operand layout)
#pragma unroll
        for (int j = 0; j < 4; ++j) {
            int kc = j * 16 + lr;
            int ks = kc >> 3;
            int kb = (kc & 7) * 2;
#pragma unroll
            for (int r = 0; r < 4; ++r) {
                int qq = lg * 4 + r;
                *(_Float16*)((char*)Ps + qq * 128 + ((ks ^ (qq & 7)) << 4) + kb) =
                    (_Float16)sacc[j][r];
            }
        }
        // PV accumulate; V B-fragments direct from global:
        // bv[jd][e] = V[k0 + kk*32 + lg*8 + e][cv + jd*16 + lr]
        {
            const _Float16* vb = QKV + (base + k0) * LDQ + cv;
#pragma unroll
            for (int kk = 0; kk < 2; ++kk) {
                f16x8 pa, bv[4];
                pa = ldsfrag(Ps, lr, kk * 4 + lg);
                const _Float16* vk = vb + (size_t)(kk * 32 + lg * 8) * LDQ + lr;
#pragma unroll
                for (int jd = 0; jd < 4; ++jd)
#pragma unroll
                    for (int e = 0; e < 8; ++e)
                        bv[jd][e] = vk[(size_t)e * LDQ + jd * 16];
                __builtin_amdgcn_s_setprio(1);
#pragma unroll
                for (int jd = 0; jd < 4; ++jd)
                    cacc[jd] = __builtin_amdgcn_mfma_f32_16x16x32_f16(pa, bv[jd], cacc[jd], 0, 0, 0);
                __builtin_amdgcn_s_setprio(0);
            }
        }
    }
    // normalize + write ctx in [b*S+s][h*64+d] layout
#pragma unroll
    for (int jd = 0; jd < 4; ++jd)
#pragma unroll
        for (int r = 0; r < 4; ++r) {
            int qq = q0 + lg * 4 + r;
            int d = h * HDIM + jd * 16 + lr;
            Og[(base + qq) * DIM + d] = (_Float16)(cacc[jd][r] / lrun[r]);
        }
}

// ---------------------------------------------------------------------------
extern "C" void kernel_launch(void* const* d_in, const int* in_sizes, int n_in,
                              void* d_out, int out_size, void* d_ws, size_t ws_size,
                              hipStream_t stream) {
    const float* x    = (const float*)d_in[0];
    const float* WQ   = (const float*)d_in[1];
    const float* WK   = (const float*)d_in[2];
    const float* WV   = (const float*)d_in[3];
    const float* Wo   = (const float*)d_in[4];
    const float* bo   = (const float*)d_in[5];
    const float* W1   = (const float*)d_in[6];
    const float* b1   = (const float*)d_in[7];
    const float* W2   = (const float*)d_in[8];
    const float* b2   = (const float*)d_in[9];
    const float* ln1s = (const float*)d_in[10];
    const float* ln1b = (const float*)d_in[11];
    const float* ln2s = (const float*)d_in[12];
    const float* ln2b = (const float*)d_in[13];
    float* out = (float*)d_out;
    char* ws = (char*)d_ws;
    const size_t MB = 1024 * 1024;
    _Float16* WTqkv = (_Float16*)(ws + 0 * MB);   // [3072][1024] = 6MB
    _Float16* WTo   = (_Float16*)(ws + 6 * MB);
    _Float16* WT1   = (_Float16*)(ws + 8 * MB);   // [4096][1024]
    _Float16* WT2   = (_Float16*)(ws + 16 * MB);  // [1024][4096]
    _Float16* h1    = (_Float16*)(ws + 24 * MB);
    _Float16* qkvb  = (_Float16*)(ws + 32 * MB);  // [4096][3072] = 24MB
    _Float16* ctx   = (_Float16*)(ws + 56 * MB);
    _Float16* h2    = (_Float16*)(ws + 64 * MB);
    _Float16* ff1   = (_Float16*)(ws + 72 * MB);  // [4096][4096] = 32MB
    float*    x2    = (float*)   (ws + 104 * MB); // fp32 residual = 16MB

    dim3 tb(32, 8);
    k_tcvt3<<<dim3(32, 32, 3), tb, 0, stream>>>(WQ, WK, WV, WTqkv);
    k_tcvt<<<dim3(32, 32), tb, 0, stream>>>(Wo, WTo, 1024, 1024);
    k_tcvt<<<dim3(128, 32), tb, 0, stream>>>(W1, WT1, 1024, 4096);
    k_tcvt<<<dim3(32, 128), tb, 0, stream>>>(W2, WT2, 4096, 1024);

    k_ln<<<MTOT, 256, 0, stream>>>(x, ln1s, ln1b, h1);

    // fused QKV: [4096,1024] x [1024,3072] -> [4096,3072]  (24x32 tiles)
    k_gemm<0><<<dim3(768), 256, 0, stream>>>(h1, WTqkv, LDQ, DIM, 24, qkvb, nullptr);

    // 4096 q-tiles of 16 rows, 4 waves per block
    k_attn<<<dim3(1024), 256, 0, stream>>>(qkvb, ctx);

    // x2 = x + ctx @ Wo + bo   (512 blocks of 128x64, 3-deep pipeline)
    k_gemm64<<<dim3(512), 256, 0, stream>>>(ctx, WTo, DIM, DIM, x2, bo, x);

    k_ln<<<MTOT, 256, 0, stream>>>(x2, ln2s, ln2b, h2);

    // ff1 = gelu(h2 @ W1 + b1)  (32x32 tiles)
    k_gemm<1><<<dim3(1024), 256, 0, stream>>>(h2, WT1, DFF, DIM, 32, ff1, b1);

    // out = x2 + ff1 @ W2 + b2  (512 blocks of 128x64, 3-deep pipeline)
    k_gemm64<<<dim3(512), 256, 0, stream>>>(ff1, WT2, DIM, DFF, out, b2, x2);
}

// Round 13
// 225.784 us; speedup vs baseline: 1.1400x; 1.0358x over previous
//
#include <hip/hip_runtime.h>
#include <hip/hip_bf16.h>

#define DIM   1024
#define NHEAD 16
#define HDIM  64
#define BATCH 4
#define SEQ   1024
#define MTOT  (BATCH*SEQ)   // 4096
#define DFF   (4*DIM)       // 4096
#define LDQ   3072          // fused QKV row stride

typedef _Float16 f16x8 __attribute__((ext_vector_type(8)));
typedef _Float16 f16x4 __attribute__((ext_vector_type(4)));
typedef float    f32x4 __attribute__((ext_vector_type(4)));

// gelu(x) = 0.5x(1+tanh(z)) == x * sigmoid(2z), z = c(x + 0.044715 x^3).
__device__ __forceinline__ float geluf(float x) {
    float z2 = 1.5957691216057308f * (x + 0.044715f * x * x * x);  // 2*c*(...)
    return x * __builtin_amdgcn_rcpf(1.0f + __expf(-z2));
}

// Swizzled LDS byte offset for tiles with 64-f16 (128 B) rows, 8 slots of 16 B.
__device__ __forceinline__ int swz_off(int row, int slot) {
    return row * 128 + ((slot ^ (row & 7)) << 4);
}
__device__ __forceinline__ f16x8 ldsfrag(const _Float16* s, int row, int slot) {
    return *(const f16x8*)((const char*)s + swz_off(row, slot));
}

// Async global->LDS staging: linear LDS dest (wave-uniform base + lane*16),
// inverse-swizzled GLOBAL source so stored layout == swizzled layout (m173).
template <int NCHUNK>
__device__ __forceinline__ void stage_async(const _Float16* __restrict__ g, int ld,
                                            _Float16* s, int w, int lane) {
    int r_in = lane >> 3;               // 0..7 row within chunk
    int sslot = lane & 7;               // stored 16B slot
    int lslot = sslot ^ r_in;           // logical slot (row&7 == r_in)
#pragma unroll
    for (int q = 0; q < NCHUNK; ++q) {
        int chunk = w * NCHUNK + q;
        int row = chunk * 8 + r_in;
        const _Float16* gp = g + (size_t)row * ld + lslot * 8;
        _Float16* sp = s + chunk * 512;  // wave-uniform
        __builtin_amdgcn_global_load_lds(
            (const __attribute__((address_space(1))) void*)gp,
            (__attribute__((address_space(3))) void*)sp, 16, 0, 0);
    }
}

// ---------------- transpose + fp32->f16 convert:  src[K][N] -> dst[N][K] ----
__global__ __launch_bounds__(256) void k_tcvt(const float* __restrict__ src,
                                              _Float16* __restrict__ dst,
                                              int K, int N) {
    __shared__ float tile[32][33];
    int n0 = blockIdx.x * 32, k0 = blockIdx.y * 32;
    int tx = threadIdx.x, ty = threadIdx.y;
#pragma unroll
    for (int i = 0; i < 32; i += 8)
        tile[ty + i][tx] = src[(size_t)(k0 + ty + i) * N + (n0 + tx)];
    __syncthreads();
#pragma unroll
    for (int i = 0; i < 32; i += 8)
        dst[(size_t)(n0 + ty + i) * K + (k0 + tx)] = (_Float16)tile[tx][ty + i];
}

// three 1024x1024 transposes in one launch (z picks the source)
__global__ __launch_bounds__(256) void k_tcvt3(const float* __restrict__ s0,
                                               const float* __restrict__ s1,
                                               const float* __restrict__ s2,
                                               _Float16* __restrict__ dst) {
    __shared__ float tile[32][33];
    const float* src = blockIdx.z == 0 ? s0 : (blockIdx.z == 1 ? s1 : s2);
    _Float16* d = dst + (size_t)blockIdx.z * (1024 * 1024);
    int n0 = blockIdx.x * 32, k0 = blockIdx.y * 32;
    int tx = threadIdx.x, ty = threadIdx.y;
#pragma unroll
    for (int i = 0; i < 32; i += 8)
        tile[ty + i][tx] = src[(size_t)(k0 + ty + i) * 1024 + (n0 + tx)];
    __syncthreads();
#pragma unroll
    for (int i = 0; i < 32; i += 8)
        d[(size_t)(n0 + ty + i) * 1024 + (k0 + tx)] = (_Float16)tile[tx][ty + i];
}

// ---------------- LayerNorm (fp32 in -> f16 out), one block per row ---------
__global__ __launch_bounds__(256) void k_ln(const float* __restrict__ x,
                                            const float* __restrict__ sc,
                                            const float* __restrict__ sh,
                                            _Float16* __restrict__ out) {
    int row = blockIdx.x;
    int t = threadIdx.x;
    float4 v = ((const float4*)(x + (size_t)row * DIM))[t];
    float sum = v.x + v.y + v.z + v.w;
    float sq  = v.x * v.x + v.y * v.y + v.z * v.z + v.w * v.w;
#pragma unroll
    for (int m = 1; m < 64; m <<= 1) {
        sum += __shfl_xor(sum, m);
        sq  += __shfl_xor(sq, m);
    }
    __shared__ float rs[4], rq[4];
    int w = t >> 6;
    if ((t & 63) == 0) { rs[w] = sum; rq[w] = sq; }
    __syncthreads();
    sum = rs[0] + rs[1] + rs[2] + rs[3];
    sq  = rq[0] + rq[1] + rq[2] + rq[3];
    float mean = sum * (1.0f / DIM);
    float var  = sq * (1.0f / DIM) - mean * mean;
    float rstd = rsqrtf(var + 1e-5f);
    float4 s4 = ((const float4*)sc)[t];
    float4 b4 = ((const float4*)sh)[t];
    f16x4 o;
    o[0] = (_Float16)(s4.x * ((v.x - mean) * rstd) + b4.x);
    o[1] = (_Float16)(s4.y * ((v.y - mean) * rstd) + b4.y);
    o[2] = (_Float16)(s4.z * ((v.z - mean) * rstd) + b4.z);
    o[3] = (_Float16)(s4.w * ((v.w - mean) * rstd) + b4.w);
    ((f16x4*)(out + (size_t)row * DIM))[t] = o;
}

// ---------------- GEMM 128x128, BK=64, 2-phase pipelined, XCD-chunked -------
// (for N>=3072 outputs: QKV, FF1 — grids 768/1024 blocks)
// EPI: 0 = plain f16; 1 = +bias,gelu f16
template <int EPI>
__global__ __launch_bounds__(256) void k_gemm(const _Float16* __restrict__ A,
                                              const _Float16* __restrict__ BT,
                                              int N, int K, int gx,
                                              _Float16* __restrict__ Ch,
                                              const float* __restrict__ bias) {
    __shared__ _Float16 As[2][128 * 64];
    __shared__ _Float16 Bs[2][128 * 64];
    int t = threadIdx.x;
    int bid = blockIdx.x;
    int lin = (bid & 7) * ((int)gridDim.x >> 3) + (bid >> 3);
    int m0 = (lin / gx) * 128, n0 = (lin % gx) * 128;
    int lane = t & 63, w = t >> 6;
    int wm = (w >> 1) * 64, wn = (w & 1) * 64;
    int lr = lane & 15, lg = lane >> 4;
    f32x4 acc[4][4];
#pragma unroll
    for (int i = 0; i < 4; ++i)
#pragma unroll
        for (int j = 0; j < 4; ++j) acc[i][j] = (f32x4){0.f, 0.f, 0.f, 0.f};

    const _Float16* Ag = A  + (size_t)m0 * K;
    const _Float16* Bg = BT + (size_t)n0 * K;
    int nt = K / 64;
    stage_async<4>(Ag, K, As[0], w, lane);
    stage_async<4>(Bg, K, Bs[0], w, lane);
    __syncthreads();
    for (int tt = 0; tt < nt; ++tt) {
        int cur = tt & 1, nxt = cur ^ 1;
        if (tt + 1 < nt) {
            stage_async<4>(Ag + (tt + 1) * 64, K, As[nxt], w, lane);
            stage_async<4>(Bg + (tt + 1) * 64, K, Bs[nxt], w, lane);
        }
#pragma unroll
        for (int kk = 0; kk < 2; ++kk) {
            f16x8 a[4], b[4];
#pragma unroll
            for (int i = 0; i < 4; ++i) a[i] = ldsfrag(As[cur], wm + i * 16 + lr, kk * 4 + lg);
#pragma unroll
            for (int j = 0; j < 4; ++j) b[j] = ldsfrag(Bs[cur], wn + j * 16 + lr, kk * 4 + lg);
            __builtin_amdgcn_s_setprio(1);
#pragma unroll
            for (int i = 0; i < 4; ++i)
#pragma unroll
                for (int j = 0; j < 4; ++j)
                    acc[i][j] = __builtin_amdgcn_mfma_f32_16x16x32_f16(a[i], b[j], acc[i][j], 0, 0, 0);
            __builtin_amdgcn_s_setprio(0);
        }
        __syncthreads();   // drains next-tile loads; guards buffer reuse
    }
#pragma unroll
    for (int i = 0; i < 4; ++i) {
#pragma unroll
        for (int j = 0; j < 4; ++j) {
            int row = m0 + wm + i * 16 + lg * 4;
            int col = n0 + wn + j * 16 + lr;
#pragma unroll
            for (int r = 0; r < 4; ++r) {
                float v = acc[i][j][r];
                size_t idx = (size_t)(row + r) * N + col;
                if constexpr (EPI == 0) Ch[idx] = (_Float16)v;
                else                    Ch[idx] = (_Float16)geluf(v + bias[col]);
            }
        }
    }
}

// ---------------- GEMM 128x64 (N=1024: Wo, FF2), 3-buffer counted-vmcnt -----
__global__ __launch_bounds__(256) void k_gemm64(const _Float16* __restrict__ A,
                                                const _Float16* __restrict__ BT,
                                                int N, int K,
                                                float* __restrict__ Cf,
                                                const float* __restrict__ bias,
                                                const float* __restrict__ resid) {
    __shared__ _Float16 As[3][128 * 64];
    __shared__ _Float16 Bs[3][64 * 64];
    int t = threadIdx.x;
    int bid = blockIdx.x;
    int lin = (bid & 7) * ((int)gridDim.x >> 3) + (bid >> 3);
    int gx = N / 64;
    int m0 = (lin / gx) * 128, n0 = (lin % gx) * 64;
    int lane = t & 63, w = t >> 6;
    int wm = w * 32;
    int lr = lane & 15, lg = lane >> 4;
    f32x4 acc[2][4];
#pragma unroll
    for (int i = 0; i < 2; ++i)
#pragma unroll
        for (int j = 0; j < 4; ++j) acc[i][j] = (f32x4){0.f, 0.f, 0.f, 0.f};

    const _Float16* Ag = A  + (size_t)m0 * K;
    const _Float16* Bg = BT + (size_t)n0 * K;
    int nt = K / 64;
    // prologue: tiles 0 and 1 in flight (12 outstanding per wave)
    stage_async<4>(Ag, K, As[0], w, lane);
    stage_async<2>(Bg, K, Bs[0], w, lane);
    stage_async<4>(Ag + 64, K, As[1], w, lane);
    stage_async<2>(Bg + 64, K, Bs[1], w, lane);
    for (int tt = 0; tt < nt; ++tt) {
        if (tt + 1 < nt) asm volatile("s_waitcnt vmcnt(6)" ::: "memory");
        else             asm volatile("s_waitcnt vmcnt(0)" ::: "memory");
        __builtin_amdgcn_sched_barrier(0);
        __builtin_amdgcn_s_barrier();
        __builtin_amdgcn_sched_barrier(0);
        const _Float16* Ac = As[tt % 3];
        const _Float16* Bc = Bs[tt % 3];
#pragma unroll
        for (int kk = 0; kk < 2; ++kk) {
            f16x8 a[2], b[4];
#pragma unroll
            for (int i = 0; i < 2; ++i) a[i] = ldsfrag(Ac, wm + i * 16 + lr, kk * 4 + lg);
#pragma unroll
            for (int j = 0; j < 4; ++j) b[j] = ldsfrag(Bc, j * 16 + lr, kk * 4 + lg);
            __builtin_amdgcn_s_setprio(1);
#pragma unroll
            for (int i = 0; i < 2; ++i)
#pragma unroll
                for (int j = 0; j < 4; ++j)
                    acc[i][j] = __builtin_amdgcn_mfma_f32_16x16x32_f16(a[i], b[j], acc[i][j], 0, 0, 0);
            __builtin_amdgcn_s_setprio(0);
        }
        if (tt + 2 < nt) {
            int nb = (tt + 2) % 3;
            stage_async<4>(Ag + (tt + 2) * 64, K, As[nb], w, lane);
            stage_async<2>(Bg + (tt + 2) * 64, K, Bs[nb], w, lane);
        }
    }
#pragma unroll
    for (int i = 0; i < 2; ++i) {
#pragma unroll
        for (int j = 0; j < 4; ++j) {
            int row = m0 + wm + i * 16 + lg * 4;
            int col = n0 + j * 16 + lr;
#pragma unroll
            for (int r = 0; r < 4; ++r) {
                size_t idx = (size_t)(row + r) * N + col;
                Cf[idx] = acc[i][j][r] + bias[col] + resid[idx];
            }
        }
    }
}

// ---------------- Flash attention: swapped-operand QK^T/PV ------------------
// 1 wave per (b, h, 32-row q-tile); LPT heavy-first grid; V direct-from-global.
// QK^T computed as mfma(K, Q): C/D col (=lane&15) indexes the Q-ROW, so each
// lane holds a full 16-wide k-slice of ONE q-row -> softmax row-reduce is an
// in-lane tree + 2 shfl_xor (vs 4-deep chains x 8). PV computed as mfma(V, P):
// accumulator col also = q-row -> rescale is lane-local. P staged via LDS in
// the A/B fragment layout (8B vector writes).
__global__ __launch_bounds__(64) void k_attn(const _Float16* __restrict__ QKV,
                                             _Float16* __restrict__ Og) {
    __shared__ _Float16 Ps[32 * 64];  // P[q][k], swizzled (4 KB)
    int lane = threadIdx.x;
    int id = blockIdx.x;
    int bh = id & 63;
    int qt = (SEQ / 32 - 1) - (id >> 6);  // heavy blocks dispatch first
    int h = bh & 15, b = bh >> 4;
    int q0 = qt * 32;
    int lr = lane & 15, lg = lane >> 4;
    size_t base = (size_t)b * SEQ;
    int cq = h * HDIM, ck = 1024 + h * HDIM, cv = 2048 + h * HDIM;

    // Q fragments (B-operand: col=lane&15 -> q-row, k=(lane>>4)*8+e), scaled
    f16x8 aq[2][2];
#pragma unroll
    for (int i = 0; i < 2; ++i)
#pragma unroll
        for (int kk = 0; kk < 2; ++kk) {
            f16x8 v = *(const f16x8*)(QKV + (base + q0 + i * 16 + lr) * LDQ + cq + kk * 32 + lg * 8);
#pragma unroll
            for (int e = 0; e < 8; ++e) v[e] = v[e] * (_Float16)0.125f;
            aq[i][kk] = v;
        }

    // cacc[i][jd]: D col=lane&15 = q-row (i*16+lr), row = d = jd*16+lg*4+r
    f32x4 cacc[2][4];
#pragma unroll
    for (int i = 0; i < 2; ++i)
#pragma unroll
        for (int j = 0; j < 4; ++j) cacc[i][j] = (f32x4){0.f, 0.f, 0.f, 0.f};
    float mrun[2], lrun[2];
#pragma unroll
    for (int i = 0; i < 2; ++i) { mrun[i] = -1e30f; lrun[i] = 0.f; }

    int ntiles = q0 / 64 + 1;   // 64-wide K/V tiles needed for causal rows
    for (int kt = 0; kt < ntiles; ++kt) {
        int k0 = kt * 64;
        // scores^T = K Q^T: sacc[i][j] col = q-row (i*16+lr), row = k (j*16+lg*4+r)
        f32x4 sacc[2][4];
#pragma unroll
        for (int i = 0; i < 2; ++i)
#pragma unroll
            for (int j = 0; j < 4; ++j) sacc[i][j] = (f32x4){0.f, 0.f, 0.f, 0.f};
#pragma unroll
        for (int kk = 0; kk < 2; ++kk) {
            f16x8 bk[4];
#pragma unroll
            for (int j = 0; j < 4; ++j)
                bk[j] = *(const f16x8*)(QKV + (base + k0 + j * 16 + lr) * LDQ + ck + kk * 32 + lg * 8);
            __builtin_amdgcn_s_setprio(1);
#pragma unroll
            for (int i = 0; i < 2; ++i)
#pragma unroll
                for (int j = 0; j < 4; ++j)
                    sacc[i][j] = __builtin_amdgcn_mfma_f32_16x16x32_f16(bk[j], aq[i][kk], sacc[i][j], 0, 0, 0);
            __builtin_amdgcn_s_setprio(0);
        }
        // causal mask (last tile only): qq = q0+i*16+lr, kc = k0+j*16+lg*4+r
        if (kt == ntiles - 1) {
#pragma unroll
            for (int i = 0; i < 2; ++i) {
                int qq = q0 + i * 16 + lr;
#pragma unroll
                for (int j = 0; j < 4; ++j)
#pragma unroll
                    for (int r = 0; r < 4; ++r) {
                        int kc = k0 + j * 16 + lg * 4 + r;
                        if (kc > qq) sacc[i][j][r] = -1e30f;
                    }
            }
        }
        // online softmax: per i, all 16 values in-lane belong to q-row i*16+lr
#pragma unroll
        for (int i = 0; i < 2; ++i) {
            float tm = -1e30f;
#pragma unroll
            for (int j = 0; j < 4; ++j)
#pragma unroll
                for (int r = 0; r < 4; ++r) tm = fmaxf(tm, sacc[i][j][r]);
            tm = fmaxf(tm, __shfl_xor(tm, 16));
            tm = fmaxf(tm, __shfl_xor(tm, 32));
            float m2 = fmaxf(mrun[i], tm);
            float al = __expf(mrun[i] - m2);
            mrun[i] = m2;
#pragma unroll
            for (int jd = 0; jd < 4; ++jd)
#pragma unroll
                for (int r = 0; r < 4; ++r) cacc[i][jd][r] *= al;
            float ps = 0.f;
#pragma unroll
            for (int j = 0; j < 4; ++j)
#pragma unroll
                for (int r = 0; r < 4; ++r) {
                    float p = __expf(sacc[i][j][r] - m2);
                    sacc[i][j][r] = p;
                    ps += p;
                }
            ps += __shfl_xor(ps, 16);
            ps += __shfl_xor(ps, 32);
            lrun[i] = lrun[i] * al + ps;
        }
        // P -> LDS: row q=i*16+lr, kc=j*16+lg*4+{0..3} consecutive -> 8B writes
#pragma unroll
        for (int i = 0; i < 2; ++i) {
            int q = i * 16 + lr;
#pragma unroll
            for (int j = 0; j < 4; ++j) {
                int kc0 = j * 16 + lg * 4;
                int ks = kc0 >> 3;
                f16x4 pv4;
#pragma unroll
                for (int r = 0; r < 4; ++r) pv4[r] = (_Float16)sacc[i][j][r];
                *(f16x4*)((char*)Ps + q * 128 + ((ks ^ (q & 7)) << 4) + (kc0 & 7) * 2) = pv4;
            }
        }
        // PV: cacc[i][jd] += mfma(V-frag as A, P as B). V direct from global:
        // bv[jd][e] = V[k0+kk*32+lg*8+e][cv + jd*16 + lr]  (A row = d-in-block)
        {
            const _Float16* vb = QKV + (base + k0) * LDQ + cv;
#pragma unroll
            for (int kk = 0; kk < 2; ++kk) {
                f16x8 pa[2], bv[4];
#pragma unroll
                for (int i = 0; i < 2; ++i) pa[i] = ldsfrag(Ps, i * 16 + lr, kk * 4 + lg);
                const _Float16* vk = vb + (size_t)(kk * 32 + lg * 8) * LDQ + lr;
#pragma unroll
                for (int jd = 0; jd < 4; ++jd)
#pragma unroll
                    for (int e = 0; e < 8; ++e)
                        bv[jd][e] = vk[(size_t)e * LDQ + jd * 16];
                __builtin_amdgcn_s_setprio(1);
#pragma unroll
                for (int i = 0; i < 2; ++i)
#pragma unroll
                    for (int jd = 0; jd < 4; ++jd)
                        cacc[i][jd] = __builtin_amdgcn_mfma_f32_16x16x32_f16(bv[jd], pa[i], cacc[i][jd], 0, 0, 0);
                __builtin_amdgcn_s_setprio(0);
            }
        }
    }
    // normalize + write ctx: q = q0+i*16+lr, d = jd*16+lg*4+{0..3} -> 8B stores
#pragma unroll
    for (int i = 0; i < 2; ++i) {
        float rl = 1.0f / lrun[i];
        int qq = q0 + i * 16 + lr;
#pragma unroll
        for (int jd = 0; jd < 4; ++jd) {
            f16x4 o4;
#pragma unroll
            for (int r = 0; r < 4; ++r) o4[r] = (_Float16)(cacc[i][jd][r] * rl);
            *(f16x4*)(Og + (base + qq) * DIM + h * HDIM + jd * 16 + lg * 4) = o4;
        }
    }
}

// ---------------------------------------------------------------------------
extern "C" void kernel_launch(void* const* d_in, const int* in_sizes, int n_in,
                              void* d_out, int out_size, void* d_ws, size_t ws_size,
                              hipStream_t stream) {
    const float* x    = (const float*)d_in[0];
    const float* WQ   = (const float*)d_in[1];
    const float* WK   = (const float*)d_in[2];
    const float* WV   = (const float*)d_in[3];
    const float* Wo   = (const float*)d_in[4];
    const float* bo   = (const float*)d_in[5];
    const float* W1   = (const float*)d_in[6];
    const float* b1   = (const float*)d_in[7];
    const float* W2   = (const float*)d_in[8];
    const float* b2   = (const float*)d_in[9];
    const float* ln1s = (const float*)d_in[10];
    const float* ln1b = (const float*)d_in[11];
    const float* ln2s = (const float*)d_in[12];
    const float* ln2b = (const float*)d_in[13];
    float* out = (float*)d_out;
    char* ws = (char*)d_ws;
    const size_t MB = 1024 * 1024;
    _Float16* WTqkv = (_Float16*)(ws + 0 * MB);   // [3072][1024] = 6MB
    _Float16* WTo   = (_Float16*)(ws + 6 * MB);
    _Float16* WT1   = (_Float16*)(ws + 8 * MB);   // [4096][1024]
    _Float16* WT2   = (_Float16*)(ws + 16 * MB);  // [1024][4096]
    _Float16* h1    = (_Float16*)(ws + 24 * MB);
    _Float16* qkvb  = (_Float16*)(ws + 32 * MB);  // [4096][3072] = 24MB
    _Float16* ctx   = (_Float16*)(ws + 56 * MB);
    _Float16* h2    = (_Float16*)(ws + 64 * MB);
    _Float16* ff1   = (_Float16*)(ws + 72 * MB);  // [4096][4096] = 32MB
    float*    x2    = (float*)   (ws + 104 * MB); // fp32 residual = 16MB

    dim3 tb(32, 8);
    k_tcvt3<<<dim3(32, 32, 3), tb, 0, stream>>>(WQ, WK, WV, WTqkv);
    k_tcvt<<<dim3(32, 32), tb, 0, stream>>>(Wo, WTo, 1024, 1024);
    k_tcvt<<<dim3(128, 32), tb, 0, stream>>>(W1, WT1, 1024, 4096);
    k_tcvt<<<dim3(32, 128), tb, 0, stream>>>(W2, WT2, 4096, 1024);

    k_ln<<<MTOT, 256, 0, stream>>>(x, ln1s, ln1b, h1);

    // fused QKV: [4096,1024] x [1024,3072] -> [4096,3072]  (24x32 tiles)
    k_gemm<0><<<dim3(768), 256, 0, stream>>>(h1, WTqkv, LDQ, DIM, 24, qkvb, nullptr);

    k_attn<<<dim3(2048), 64, 0, stream>>>(qkvb, ctx);

    // x2 = x + ctx @ Wo + bo   (512 blocks of 128x64, 3-deep pipeline)
    k_gemm64<<<dim3(512), 256, 0, stream>>>(ctx, WTo, DIM, DIM, x2, bo, x);

    k_ln<<<MTOT, 256, 0, stream>>>(x2, ln2s, ln2b, h2);

    // ff1 = gelu(h2 @ W1 + b1)  (32x32 tiles)
    k_gemm<1><<<dim3(1024), 256, 0, stream>>>(h2, WT1, DFF, DIM, 32, ff1, b1);

    // out = x2 + ff1 @ W2 + b2  (512 blocks of 128x64, 3-deep pipeline)
    k_gemm64<<<dim3(512), 256, 0, stream>>>(ff1, WT2, DIM, DFF, out, b2, x2);
}

// Round 14
// 223.360 us; speedup vs baseline: 1.1524x; 1.0109x over previous
//
#include <hip/hip_runtime.h>
#include <hip/hip_bf16.h>

#define DIM   1024
#define NHEAD 16
#define HDIM  64
#define BATCH 4
#define SEQ   1024
#define MTOT  (BATCH*SEQ)   // 4096
#define DFF   (4*DIM)       // 4096
#define LDQ   3072          // fused QKV row stride

typedef _Float16 f16x8 __attribute__((ext_vector_type(8)));
typedef _Float16 f16x4 __attribute__((ext_vector_type(4)));
typedef float    f32x4 __attribute__((ext_vector_type(4)));

// gelu(x) = 0.5x(1+tanh(z)) == x * sigmoid(2z), z = c(x + 0.044715 x^3).
__device__ __forceinline__ float geluf(float x) {
    float z2 = 1.5957691216057308f * (x + 0.044715f * x * x * x);  // 2*c*(...)
    return x * __builtin_amdgcn_rcpf(1.0f + __expf(-z2));
}

// Swizzled LDS byte offset for tiles with 64-f16 (128 B) rows, 8 slots of 16 B.
__device__ __forceinline__ int swz_off(int row, int slot) {
    return row * 128 + ((slot ^ (row & 7)) << 4);
}
__device__ __forceinline__ f16x8 ldsfrag(const _Float16* s, int row, int slot) {
    return *(const f16x8*)((const char*)s + swz_off(row, slot));
}

// Async global->LDS staging: linear LDS dest (wave-uniform base + lane*16),
// inverse-swizzled GLOBAL source so stored layout == swizzled layout (m173).
template <int NCHUNK>
__device__ __forceinline__ void stage_async(const _Float16* __restrict__ g, int ld,
                                            _Float16* s, int w, int lane) {
    int r_in = lane >> 3;               // 0..7 row within chunk
    int sslot = lane & 7;               // stored 16B slot
    int lslot = sslot ^ r_in;           // logical slot (row&7 == r_in)
#pragma unroll
    for (int q = 0; q < NCHUNK; ++q) {
        int chunk = w * NCHUNK + q;
        int row = chunk * 8 + r_in;
        const _Float16* gp = g + (size_t)row * ld + lslot * 8;
        _Float16* sp = s + chunk * 512;  // wave-uniform
        __builtin_amdgcn_global_load_lds(
            (const __attribute__((address_space(1))) void*)gp,
            (__attribute__((address_space(3))) void*)sp, 16, 0, 0);
    }
}

// ---------------- transpose + fp32->f16 convert:  src[K][N] -> dst[N][K] ----
__global__ __launch_bounds__(256) void k_tcvt(const float* __restrict__ src,
                                              _Float16* __restrict__ dst,
                                              int K, int N) {
    __shared__ float tile[32][33];
    int n0 = blockIdx.x * 32, k0 = blockIdx.y * 32;
    int tx = threadIdx.x, ty = threadIdx.y;
#pragma unroll
    for (int i = 0; i < 32; i += 8)
        tile[ty + i][tx] = src[(size_t)(k0 + ty + i) * N + (n0 + tx)];
    __syncthreads();
#pragma unroll
    for (int i = 0; i < 32; i += 8)
        dst[(size_t)(n0 + ty + i) * K + (k0 + tx)] = (_Float16)tile[tx][ty + i];
}

// four 1024x1024 transposes in one launch (z picks the source; dst slices are
// contiguous: z=0..2 -> WTqkv, z=3 -> WTo which sits right after in ws)
__global__ __launch_bounds__(256) void k_tcvt4(const float* __restrict__ s0,
                                               const float* __restrict__ s1,
                                               const float* __restrict__ s2,
                                               const float* __restrict__ s3,
                                               _Float16* __restrict__ dst) {
    __shared__ float tile[32][33];
    const float* src = blockIdx.z == 0 ? s0 : (blockIdx.z == 1 ? s1 :
                       (blockIdx.z == 2 ? s2 : s3));
    _Float16* d = dst + (size_t)blockIdx.z * (1024 * 1024);
    int n0 = blockIdx.x * 32, k0 = blockIdx.y * 32;
    int tx = threadIdx.x, ty = threadIdx.y;
#pragma unroll
    for (int i = 0; i < 32; i += 8)
        tile[ty + i][tx] = src[(size_t)(k0 + ty + i) * 1024 + (n0 + tx)];
    __syncthreads();
#pragma unroll
    for (int i = 0; i < 32; i += 8)
        d[(size_t)(n0 + ty + i) * 1024 + (k0 + tx)] = (_Float16)tile[tx][ty + i];
}

// ---------------- LayerNorm (fp32 in -> f16 out), one block per row ---------
__global__ __launch_bounds__(256) void k_ln(const float* __restrict__ x,
                                            const float* __restrict__ sc,
                                            const float* __restrict__ sh,
                                            _Float16* __restrict__ out) {
    int row = blockIdx.x;
    int t = threadIdx.x;
    float4 v = ((const float4*)(x + (size_t)row * DIM))[t];
    float sum = v.x + v.y + v.z + v.w;
    float sq  = v.x * v.x + v.y * v.y + v.z * v.z + v.w * v.w;
#pragma unroll
    for (int m = 1; m < 64; m <<= 1) {
        sum += __shfl_xor(sum, m);
        sq  += __shfl_xor(sq, m);
    }
    __shared__ float rs[4], rq[4];
    int w = t >> 6;
    if ((t & 63) == 0) { rs[w] = sum; rq[w] = sq; }
    __syncthreads();
    sum = rs[0] + rs[1] + rs[2] + rs[3];
    sq  = rq[0] + rq[1] + rq[2] + rq[3];
    float mean = sum * (1.0f / DIM);
    float var  = sq * (1.0f / DIM) - mean * mean;
    float rstd = rsqrtf(var + 1e-5f);
    float4 s4 = ((const float4*)sc)[t];
    float4 b4 = ((const float4*)sh)[t];
    f16x4 o;
    o[0] = (_Float16)(s4.x * ((v.x - mean) * rstd) + b4.x);
    o[1] = (_Float16)(s4.y * ((v.y - mean) * rstd) + b4.y);
    o[2] = (_Float16)(s4.z * ((v.z - mean) * rstd) + b4.z);
    o[3] = (_Float16)(s4.w * ((v.w - mean) * rstd) + b4.w);
    ((f16x4*)(out + (size_t)row * DIM))[t] = o;
}

// ---------------- GEMM 128x128, BK=64, counted-vmcnt 2-phase, XCD-chunked ---
// Per iter: issue stage(t+1) FIRST, then s_waitcnt vmcnt(8) -> only the
// oldest 8 (tile t's loads) are waited; never drain to 0 mid-loop (T4, the
// proven k_gemm64 pattern). Barrier publishes all waves' tile-t loads; end
// barrier guards buffer reuse. EPI: 0 = plain f16; 1 = +bias,gelu f16
template <int EPI>
__global__ __launch_bounds__(256) void k_gemm(const _Float16* __restrict__ A,
                                              const _Float16* __restrict__ BT,
                                              int N, int K, int gx,
                                              _Float16* __restrict__ Ch,
                                              const float* __restrict__ bias) {
    __shared__ _Float16 As[2][128 * 64];
    __shared__ _Float16 Bs[2][128 * 64];
    int t = threadIdx.x;
    int bid = blockIdx.x;
    int lin = (bid & 7) * ((int)gridDim.x >> 3) + (bid >> 3);
    int m0 = (lin / gx) * 128, n0 = (lin % gx) * 128;
    int lane = t & 63, w = t >> 6;
    int wm = (w >> 1) * 64, wn = (w & 1) * 64;
    int lr = lane & 15, lg = lane >> 4;
    f32x4 acc[4][4];
#pragma unroll
    for (int i = 0; i < 4; ++i)
#pragma unroll
        for (int j = 0; j < 4; ++j) acc[i][j] = (f32x4){0.f, 0.f, 0.f, 0.f};

    const _Float16* Ag = A  + (size_t)m0 * K;
    const _Float16* Bg = BT + (size_t)n0 * K;
    int nt = K / 64;
    stage_async<4>(Ag, K, As[0], w, lane);
    stage_async<4>(Bg, K, Bs[0], w, lane);
    for (int tt = 0; tt < nt; ++tt) {
        int cur = tt & 1, nxt = cur ^ 1;
        if (tt + 1 < nt) {
            stage_async<4>(Ag + (tt + 1) * 64, K, As[nxt], w, lane);
            stage_async<4>(Bg + (tt + 1) * 64, K, Bs[nxt], w, lane);
            asm volatile("s_waitcnt vmcnt(8)" ::: "memory");
        } else {
            asm volatile("s_waitcnt vmcnt(0)" ::: "memory");
        }
        __builtin_amdgcn_sched_barrier(0);
        __builtin_amdgcn_s_barrier();
        __builtin_amdgcn_sched_barrier(0);
#pragma unroll
        for (int kk = 0; kk < 2; ++kk) {
            f16x8 a[4], b[4];
#pragma unroll
            for (int i = 0; i < 4; ++i) a[i] = ldsfrag(As[cur], wm + i * 16 + lr, kk * 4 + lg);
#pragma unroll
            for (int j = 0; j < 4; ++j) b[j] = ldsfrag(Bs[cur], wn + j * 16 + lr, kk * 4 + lg);
            __builtin_amdgcn_s_setprio(1);
#pragma unroll
            for (int i = 0; i < 4; ++i)
#pragma unroll
                for (int j = 0; j < 4; ++j)
                    acc[i][j] = __builtin_amdgcn_mfma_f32_16x16x32_f16(a[i], b[j], acc[i][j], 0, 0, 0);
            __builtin_amdgcn_s_setprio(0);
        }
        __builtin_amdgcn_s_barrier();   // buf[cur] reads done before overwrite
    }
#pragma unroll
    for (int i = 0; i < 4; ++i) {
#pragma unroll
        for (int j = 0; j < 4; ++j) {
            int row = m0 + wm + i * 16 + lg * 4;
            int col = n0 + wn + j * 16 + lr;
#pragma unroll
            for (int r = 0; r < 4; ++r) {
                float v = acc[i][j][r];
                size_t idx = (size_t)(row + r) * N + col;
                if constexpr (EPI == 0) Ch[idx] = (_Float16)v;
                else                    Ch[idx] = (_Float16)geluf(v + bias[col]);
            }
        }
    }
}

// ---------------- GEMM 128x64 (N=1024: Wo, FF2), 3-buffer counted-vmcnt -----
__global__ __launch_bounds__(256) void k_gemm64(const _Float16* __restrict__ A,
                                                const _Float16* __restrict__ BT,
                                                int N, int K,
                                                float* __restrict__ Cf,
                                                const float* __restrict__ bias,
                                                const float* __restrict__ resid) {
    __shared__ _Float16 As[3][128 * 64];
    __shared__ _Float16 Bs[3][64 * 64];
    int t = threadIdx.x;
    int bid = blockIdx.x;
    int lin = (bid & 7) * ((int)gridDim.x >> 3) + (bid >> 3);
    int gx = N / 64;
    int m0 = (lin / gx) * 128, n0 = (lin % gx) * 64;
    int lane = t & 63, w = t >> 6;
    int wm = w * 32;
    int lr = lane & 15, lg = lane >> 4;
    f32x4 acc[2][4];
#pragma unroll
    for (int i = 0; i < 2; ++i)
#pragma unroll
        for (int j = 0; j < 4; ++j) acc[i][j] = (f32x4){0.f, 0.f, 0.f, 0.f};

    const _Float16* Ag = A  + (size_t)m0 * K;
    const _Float16* Bg = BT + (size_t)n0 * K;
    int nt = K / 64;
    // prologue: tiles 0 and 1 in flight (12 outstanding per wave)
    stage_async<4>(Ag, K, As[0], w, lane);
    stage_async<2>(Bg, K, Bs[0], w, lane);
    stage_async<4>(Ag + 64, K, As[1], w, lane);
    stage_async<2>(Bg + 64, K, Bs[1], w, lane);
    for (int tt = 0; tt < nt; ++tt) {
        if (tt + 1 < nt) asm volatile("s_waitcnt vmcnt(6)" ::: "memory");
        else             asm volatile("s_waitcnt vmcnt(0)" ::: "memory");
        __builtin_amdgcn_sched_barrier(0);
        __builtin_amdgcn_s_barrier();
        __builtin_amdgcn_sched_barrier(0);
        const _Float16* Ac = As[tt % 3];
        const _Float16* Bc = Bs[tt % 3];
#pragma unroll
        for (int kk = 0; kk < 2; ++kk) {
            f16x8 a[2], b[4];
#pragma unroll
            for (int i = 0; i < 2; ++i) a[i] = ldsfrag(Ac, wm + i * 16 + lr, kk * 4 + lg);
#pragma unroll
            for (int j = 0; j < 4; ++j) b[j] = ldsfrag(Bc, j * 16 + lr, kk * 4 + lg);
            __builtin_amdgcn_s_setprio(1);
#pragma unroll
            for (int i = 0; i < 2; ++i)
#pragma unroll
                for (int j = 0; j < 4; ++j)
                    acc[i][j] = __builtin_amdgcn_mfma_f32_16x16x32_f16(a[i], b[j], acc[i][j], 0, 0, 0);
            __builtin_amdgcn_s_setprio(0);
        }
        if (tt + 2 < nt) {
            int nb = (tt + 2) % 3;
            stage_async<4>(Ag + (tt + 2) * 64, K, As[nb], w, lane);
            stage_async<2>(Bg + (tt + 2) * 64, K, Bs[nb], w, lane);
        }
    }
#pragma unroll
    for (int i = 0; i < 2; ++i) {
#pragma unroll
        for (int j = 0; j < 4; ++j) {
            int row = m0 + wm + i * 16 + lg * 4;
            int col = n0 + j * 16 + lr;
#pragma unroll
            for (int r = 0; r < 4; ++r) {
                size_t idx = (size_t)(row + r) * N + col;
                Cf[idx] = acc[i][j][r] + bias[col] + resid[idx];
            }
        }
    }
}

// ---------------- Flash attention: swapped-operand QK^T/PV ------------------
// 1 wave per (b, h, 32-row q-tile); LPT heavy-first grid; V direct-from-global.
// QK^T computed as mfma(K, Q): C/D col (=lane&15) indexes the Q-ROW, so each
// lane holds a full 16-wide k-slice of ONE q-row -> softmax row-reduce is an
// in-lane tree + 2 shfl_xor. PV computed as mfma(V, P): accumulator col also
// = q-row -> rescale is lane-local. P staged via LDS (8B vector writes).
__global__ __launch_bounds__(64) void k_attn(const _Float16* __restrict__ QKV,
                                             _Float16* __restrict__ Og) {
    __shared__ _Float16 Ps[32 * 64];  // P[q][k], swizzled (4 KB)
    int lane = threadIdx.x;
    int id = blockIdx.x;
    int bh = id & 63;
    int qt = (SEQ / 32 - 1) - (id >> 6);  // heavy blocks dispatch first
    int h = bh & 15, b = bh >> 4;
    int q0 = qt * 32;
    int lr = lane & 15, lg = lane >> 4;
    size_t base = (size_t)b * SEQ;
    int cq = h * HDIM, ck = 1024 + h * HDIM, cv = 2048 + h * HDIM;

    // Q fragments (B-operand: col=lane&15 -> q-row, k=(lane>>4)*8+e), scaled
    f16x8 aq[2][2];
#pragma unroll
    for (int i = 0; i < 2; ++i)
#pragma unroll
        for (int kk = 0; kk < 2; ++kk) {
            f16x8 v = *(const f16x8*)(QKV + (base + q0 + i * 16 + lr) * LDQ + cq + kk * 32 + lg * 8);
#pragma unroll
            for (int e = 0; e < 8; ++e) v[e] = v[e] * (_Float16)0.125f;
            aq[i][kk] = v;
        }

    // cacc[i][jd]: D col=lane&15 = q-row (i*16+lr), row = d = jd*16+lg*4+r
    f32x4 cacc[2][4];
#pragma unroll
    for (int i = 0; i < 2; ++i)
#pragma unroll
        for (int j = 0; j < 4; ++j) cacc[i][j] = (f32x4){0.f, 0.f, 0.f, 0.f};
    float mrun[2], lrun[2];
#pragma unroll
    for (int i = 0; i < 2; ++i) { mrun[i] = -1e30f; lrun[i] = 0.f; }

    int ntiles = q0 / 64 + 1;   // 64-wide K/V tiles needed for causal rows
    for (int kt = 0; kt < ntiles; ++kt) {
        int k0 = kt * 64;
        // scores^T = K Q^T: sacc[i][j] col = q-row (i*16+lr), row = k (j*16+lg*4+r)
        f32x4 sacc[2][4];
#pragma unroll
        for (int i = 0; i < 2; ++i)
#pragma unroll
            for (int j = 0; j < 4; ++j) sacc[i][j] = (f32x4){0.f, 0.f, 0.f, 0.f};
#pragma unroll
        for (int kk = 0; kk < 2; ++kk) {
            f16x8 bk[4];
#pragma unroll
            for (int j = 0; j < 4; ++j)
                bk[j] = *(const f16x8*)(QKV + (base + k0 + j * 16 + lr) * LDQ + ck + kk * 32 + lg * 8);
            __builtin_amdgcn_s_setprio(1);
#pragma unroll
            for (int i = 0; i < 2; ++i)
#pragma unroll
                for (int j = 0; j < 4; ++j)
                    sacc[i][j] = __builtin_amdgcn_mfma_f32_16x16x32_f16(bk[j], aq[i][kk], sacc[i][j], 0, 0, 0);
            __builtin_amdgcn_s_setprio(0);
        }
        // causal mask (last tile only): qq = q0+i*16+lr, kc = k0+j*16+lg*4+r
        if (kt == ntiles - 1) {
#pragma unroll
            for (int i = 0; i < 2; ++i) {
                int qq = q0 + i * 16 + lr;
#pragma unroll
                for (int j = 0; j < 4; ++j)
#pragma unroll
                    for (int r = 0; r < 4; ++r) {
                        int kc = k0 + j * 16 + lg * 4 + r;
                        if (kc > qq) sacc[i][j][r] = -1e30f;
                    }
            }
        }
        // online softmax: per i, all 16 values in-lane belong to q-row i*16+lr
#pragma unroll
        for (int i = 0; i < 2; ++i) {
            float tm = -1e30f;
#pragma unroll
            for (int j = 0; j < 4; ++j)
#pragma unroll
                for (int r = 0; r < 4; ++r) tm = fmaxf(tm, sacc[i][j][r]);
            tm = fmaxf(tm, __shfl_xor(tm, 16));
            tm = fmaxf(tm, __shfl_xor(tm, 32));
            float m2 = fmaxf(mrun[i], tm);
            float al = __expf(mrun[i] - m2);
            mrun[i] = m2;
#pragma unroll
            for (int jd = 0; jd < 4; ++jd)
#pragma unroll
                for (int r = 0; r < 4; ++r) cacc[i][jd][r] *= al;
            float ps = 0.f;
#pragma unroll
            for (int j = 0; j < 4; ++j)
#pragma unroll
                for (int r = 0; r < 4; ++r) {
                    float p = __expf(sacc[i][j][r] - m2);
                    sacc[i][j][r] = p;
                    ps += p;
                }
            ps += __shfl_xor(ps, 16);
            ps += __shfl_xor(ps, 32);
            lrun[i] = lrun[i] * al + ps;
        }
        // P -> LDS: row q=i*16+lr, kc=j*16+lg*4+{0..3} consecutive -> 8B writes
#pragma unroll
        for (int i = 0; i < 2; ++i) {
            int q = i * 16 + lr;
#pragma unroll
            for (int j = 0; j < 4; ++j) {
                int kc0 = j * 16 + lg * 4;
                int ks = kc0 >> 3;
                f16x4 pv4;
#pragma unroll
                for (int r = 0; r < 4; ++r) pv4[r] = (_Float16)sacc[i][j][r];
                *(f16x4*)((char*)Ps + q * 128 + ((ks ^ (q & 7)) << 4) + (kc0 & 7) * 2) = pv4;
            }
        }
        // PV: cacc[i][jd] += mfma(V-frag as A, P as B). V direct from global:
        // bv[jd][e] = V[k0+kk*32+lg*8+e][cv + jd*16 + lr]  (A row = d-in-block)
        {
            const _Float16* vb = QKV + (base + k0) * LDQ + cv;
#pragma unroll
            for (int kk = 0; kk < 2; ++kk) {
                f16x8 pa[2], bv[4];
#pragma unroll
                for (int i = 0; i < 2; ++i) pa[i] = ldsfrag(Ps, i * 16 + lr, kk * 4 + lg);
                const _Float16* vk = vb + (size_t)(kk * 32 + lg * 8) * LDQ + lr;
#pragma unroll
                for (int jd = 0; jd < 4; ++jd)
#pragma unroll
                    for (int e = 0; e < 8; ++e)
                        bv[jd][e] = vk[(size_t)e * LDQ + jd * 16];
                __builtin_amdgcn_s_setprio(1);
#pragma unroll
                for (int i = 0; i < 2; ++i)
#pragma unroll
                    for (int jd = 0; jd < 4; ++jd)
                        cacc[i][jd] = __builtin_amdgcn_mfma_f32_16x16x32_f16(bv[jd], pa[i], cacc[i][jd], 0, 0, 0);
                __builtin_amdgcn_s_setprio(0);
            }
        }
    }
    // normalize + write ctx: q = q0+i*16+lr, d = jd*16+lg*4+{0..3} -> 8B stores
#pragma unroll
    for (int i = 0; i < 2; ++i) {
        float rl = 1.0f / lrun[i];
        int qq = q0 + i * 16 + lr;
#pragma unroll
        for (int jd = 0; jd < 4; ++jd) {
            f16x4 o4;
#pragma unroll
            for (int r = 0; r < 4; ++r) o4[r] = (_Float16)(cacc[i][jd][r] * rl);
            *(f16x4*)(Og + (base + qq) * DIM + h * HDIM + jd * 16 + lg * 4) = o4;
        }
    }
}

// ---------------------------------------------------------------------------
extern "C" void kernel_launch(void* const* d_in, const int* in_sizes, int n_in,
                              void* d_out, int out_size, void* d_ws, size_t ws_size,
                              hipStream_t stream) {
    const float* x    = (const float*)d_in[0];
    const float* WQ   = (const float*)d_in[1];
    const float* WK   = (const float*)d_in[2];
    const float* WV   = (const float*)d_in[3];
    const float* Wo   = (const float*)d_in[4];
    const float* bo   = (const float*)d_in[5];
    const float* W1   = (const float*)d_in[6];
    const float* b1   = (const float*)d_in[7];
    const float* W2   = (const float*)d_in[8];
    const float* b2   = (const float*)d_in[9];
    const float* ln1s = (const float*)d_in[10];
    const float* ln1b = (const float*)d_in[11];
    const float* ln2s = (const float*)d_in[12];
    const float* ln2b = (const float*)d_in[13];
    float* out = (float*)d_out;
    char* ws = (char*)d_ws;
    const size_t MB = 1024 * 1024;
    _Float16* WTqkv = (_Float16*)(ws + 0 * MB);   // [3072][1024] = 6MB
    _Float16* WTo   = (_Float16*)(ws + 6 * MB);   // contiguous after WTqkv
    _Float16* WT1   = (_Float16*)(ws + 8 * MB);   // [4096][1024]
    _Float16* WT2   = (_Float16*)(ws + 16 * MB);  // [1024][4096]
    _Float16* h1    = (_Float16*)(ws + 24 * MB);
    _Float16* qkvb  = (_Float16*)(ws + 32 * MB);  // [4096][3072] = 24MB
    _Float16* ctx   = (_Float16*)(ws + 56 * MB);
    _Float16* h2    = (_Float16*)(ws + 64 * MB);
    _Float16* ff1   = (_Float16*)(ws + 72 * MB);  // [4096][4096] = 32MB
    float*    x2    = (float*)   (ws + 104 * MB); // fp32 residual = 16MB

    dim3 tb(32, 8);
    k_tcvt4<<<dim3(32, 32, 4), tb, 0, stream>>>(WQ, WK, WV, Wo, WTqkv);
    k_tcvt<<<dim3(128, 32), tb, 0, stream>>>(W1, WT1, 1024, 4096);
    k_tcvt<<<dim3(32, 128), tb, 0, stream>>>(W2, WT2, 4096, 1024);

    k_ln<<<MTOT, 256, 0, stream>>>(x, ln1s, ln1b, h1);

    // fused QKV: [4096,1024] x [1024,3072] -> [4096,3072]  (24x32 tiles)
    k_gemm<0><<<dim3(768), 256, 0, stream>>>(h1, WTqkv, LDQ, DIM, 24, qkvb, nullptr);

    k_attn<<<dim3(2048), 64, 0, stream>>>(qkvb, ctx);

    // x2 = x + ctx @ Wo + bo   (512 blocks of 128x64, 3-deep pipeline)
    k_gemm64<<<dim3(512), 256, 0, stream>>>(ctx, WTo, DIM, DIM, x2, bo, x);

    k_ln<<<MTOT, 256, 0, stream>>>(x2, ln2s, ln2b, h2);

    // ff1 = gelu(h2 @ W1 + b1)  (32x32 tiles)
    k_gemm<1><<<dim3(1024), 256, 0, stream>>>(h2, WT1, DFF, DIM, 32, ff1, b1);

    // out = x2 + ff1 @ W2 + b2  (512 blocks of 128x64, 3-deep pipeline)
    k_gemm64<<<dim3(512), 256, 0, stream>>>(ff1, WT2, DIM, DFF, out, b2, x2);
}